// Round 2
// baseline (5150.615 us; speedup 1.0000x reference)
//
#include <hip/hip_runtime.h>
#include <math.h>

static constexpr int kN = 10000;
static constexpr int kD = 1024;
static constexpr int kR = 8;
static constexpr int kE = 80000;

__global__ void zero_f32(float* __restrict__ p, long n) {
    long i = (long)blockIdx.x * blockDim.x + threadIdx.x;
    long stride = (long)gridDim.x * blockDim.x;
    for (; i < n; i += stride) p[i] = 0.0f;
}

__global__ void count_edges(const int* __restrict__ etype, const int* __restrict__ dst,
                            float* __restrict__ cnt) {
    int e = blockIdx.x * blockDim.x + threadIdx.x;
    if (e < kE) atomicAdd(&cnt[etype[e] * kN + dst[e]], 1.0f);
}

__global__ void make_rscale(float* __restrict__ cnt) {
    int i = blockIdx.x * blockDim.x + threadIdx.x;
    if (i < kR * kN) {
        float c = cnt[i];
        cnt[i] = 1.0f / fmaxf(c, 1.0f);
    }
}

// One block per edge; 256 threads x 4 floats = D=1024.
__global__ void scatter_edges(const float* __restrict__ x, const int* __restrict__ src,
                              const int* __restrict__ dst, const int* __restrict__ etype,
                              int rel, float* __restrict__ mean) {
    int e = blockIdx.x;
    if (etype[e] != rel) return;
    int s = src[e], t = dst[e];
    int d = threadIdx.x << 2;
    float4 v = *reinterpret_cast<const float4*>(x + (size_t)s * kD + d);
    float* mp = mean + (size_t)t * kD + d;
    atomicAdd(mp + 0, v.x);
    atomicAdd(mp + 1, v.y);
    atomicAdd(mp + 2, v.z);
    atomicAdd(mp + 3, v.w);
}

// C[M,NC] (+)= (rowscale .* A[M,K]) @ B[K,NC]  (+ bias), fp32 accumulate.
// 64x64 tile, BK=16, 256 threads, each thread 4x4 outputs.
__global__ __launch_bounds__(256) void gemm64(const float* __restrict__ A,
                                              const float* __restrict__ B,
                                              float* __restrict__ C, int M, int K, int NC,
                                              const float* __restrict__ rowscale,
                                              const float* __restrict__ bias, int accumulate) {
    __shared__ float sA[16][68];   // [k][m], padded stride 68 (16B-aligned)
    __shared__ float sB[16][68];   // [k][n]

    const int tid = threadIdx.x;
    const int tx = tid & 15, ty = tid >> 4;
    const int row0 = blockIdx.y * 64;
    const int col0 = blockIdx.x * 64;

    const int am = tid >> 2;          // 0..63 : tile row this thread loads
    const int ak = (tid & 3) << 2;    // 0,4,8,12 : k offset (4 consecutive)
    const int bk = tid >> 4;          // 0..15 : tile k-row this thread loads
    const int bn = (tid & 15) << 2;   // 0..60 : 4 consecutive cols

    float acc[4][4] = {{0.0f}};

    const int arow = row0 + am;
    float ascale = 1.0f;
    if (rowscale != nullptr && arow < M) ascale = rowscale[arow];
    const float* Ap = A + (size_t)arow * K + ak;
    const float* Bp = B + (size_t)bk * NC + col0 + bn;

    for (int k0 = 0; k0 < K; k0 += 16) {
        float4 av;
        if (arow < M) {
            av = *reinterpret_cast<const float4*>(Ap + k0);
            av.x *= ascale; av.y *= ascale; av.z *= ascale; av.w *= ascale;
        } else {
            av = make_float4(0.f, 0.f, 0.f, 0.f);
        }
        float4 bv4 = *reinterpret_cast<const float4*>(Bp + (size_t)k0 * NC);

        __syncthreads();
        sA[ak + 0][am] = av.x; sA[ak + 1][am] = av.y;
        sA[ak + 2][am] = av.z; sA[ak + 3][am] = av.w;
        sB[bk][bn + 0] = bv4.x; sB[bk][bn + 1] = bv4.y;
        sB[bk][bn + 2] = bv4.z; sB[bk][bn + 3] = bv4.w;
        __syncthreads();

#pragma unroll
        for (int k = 0; k < 16; ++k) {
            const float4 a = *reinterpret_cast<const float4*>(&sA[k][ty << 2]);
            const float4 b = *reinterpret_cast<const float4*>(&sB[k][tx << 2]);
            acc[0][0] += a.x * b.x; acc[0][1] += a.x * b.y; acc[0][2] += a.x * b.z; acc[0][3] += a.x * b.w;
            acc[1][0] += a.y * b.x; acc[1][1] += a.y * b.y; acc[1][2] += a.y * b.z; acc[1][3] += a.y * b.w;
            acc[2][0] += a.z * b.x; acc[2][1] += a.z * b.y; acc[2][2] += a.z * b.z; acc[2][3] += a.z * b.w;
            acc[3][0] += a.w * b.x; acc[3][1] += a.w * b.y; acc[3][2] += a.w * b.z; acc[3][3] += a.w * b.w;
        }
    }

    const int col = col0 + (tx << 2);
    float4 bv = make_float4(0.f, 0.f, 0.f, 0.f);
    if (bias != nullptr) bv = *reinterpret_cast<const float4*>(bias + col);
#pragma unroll
    for (int i = 0; i < 4; ++i) {
        int row = row0 + (ty << 2) + i;
        if (row >= M) break;
        float* cp = C + (size_t)row * NC + col;
        float4 o = make_float4(acc[i][0] + bv.x, acc[i][1] + bv.y,
                               acc[i][2] + bv.z, acc[i][3] + bv.w);
        if (accumulate) {
            float4 old = *reinterpret_cast<float4*>(cp);
            o.x += old.x; o.y += old.y; o.z += old.z; o.w += old.w;
        }
        *reinterpret_cast<float4*>(cp) = o;
    }
}

__global__ void combine(const float* __restrict__ u, const float* __restrict__ z,
                        const float* __restrict__ x, float* __restrict__ out, long n) {
    long i = (long)blockIdx.x * blockDim.x + threadIdx.x;
    long stride = (long)gridDim.x * blockDim.x;
    for (; i < n; i += stride) {
        float uv = u[i];
        float zv = z[i];
        float xv = x[i];
        out[i] = tanhf(uv) * zv + xv * (1.0f - zv);
    }
}

extern "C" void kernel_launch(void* const* d_in, const int* in_sizes, int n_in,
                              void* d_out, int out_size, void* d_ws, size_t ws_size,
                              hipStream_t stream) {
    (void)in_sizes; (void)n_in; (void)out_size; (void)ws_size;

    const float* x     = (const float*)d_in[0];
    const int* eidx    = (const int*)d_in[1];
    const int* etype   = (const int*)d_in[2];
    const float* weight= (const float*)d_in[3];
    const float* root  = (const float*)d_in[4];
    const float* bias  = (const float*)d_in[5];
    const float* wgate = (const float*)d_in[6];
    const float* bgate = (const float*)d_in[7];
    float* out = (float*)d_out;

    const int* src = eidx;          // edge_index[0]
    const int* dst = eidx + kE;     // edge_index[1]

    float* u    = (float*)d_ws;                 // [kN*kD]
    float* mean = u + (size_t)kN * kD;          // [kN*kD]  (reused as z)
    float* cnt  = mean + (size_t)kN * kD;       // [kR*kN]  (becomes rscale)

    zero_f32<<<256, 256, 0, stream>>>(cnt, (long)kR * kN);
    count_edges<<<(kE + 255) / 256, 256, 0, stream>>>(etype, dst, cnt);
    make_rscale<<<(kR * kN + 255) / 256, 256, 0, stream>>>(cnt);

    dim3 g(kD / 64, (kN + 63) / 64);

    // u = x @ root + bias
    gemm64<<<g, 256, 0, stream>>>(x, root, u, kN, kD, kD, nullptr, bias, 0);

    // u += mean_r @ W_r for each relation
    for (int r = 0; r < kR; ++r) {
        zero_f32<<<2048, 256, 0, stream>>>(mean, (long)kN * kD);
        scatter_edges<<<kE, 256, 0, stream>>>(x, src, dst, etype, r, mean);
        gemm64<<<g, 256, 0, stream>>>(mean, weight + (size_t)r * kD * kD, u,
                                      kN, kD, kD, cnt + (size_t)r * kN, nullptr, 1);
    }

    // z = u @ Wg_top + x @ Wg_bot + b_gate   (z lives in mean buffer)
    gemm64<<<g, 256, 0, stream>>>(u, wgate, mean, kN, kD, kD, nullptr, bgate, 0);
    gemm64<<<g, 256, 0, stream>>>(x, wgate + (size_t)kD * kD, mean, kN, kD, kD,
                                  nullptr, nullptr, 1);

    // h = tanh(u)*z + x*(1-z)
    combine<<<2048, 256, 0, stream>>>(u, mean, x, out, (long)kN * kD);
}

// Round 3
// 2080.579 us; speedup vs baseline: 2.4756x; 2.4756x over previous
//
#include <hip/hip_runtime.h>
#include <math.h>

typedef unsigned short u16;
typedef __attribute__((ext_vector_type(8))) short bf16x8;   // 8 bf16 = 4 VGPRs
typedef __attribute__((ext_vector_type(4))) float f32x4;

static constexpr int kN = 10000;
static constexpr int kNpad = 10112;   // 79 * 128
static constexpr int kD = 1024;
static constexpr int kR = 8;
static constexpr int kE = 80000;

#define GLB(p) ((const __attribute__((address_space(1))) unsigned int*)(const void*)(p))
#define LDSP(p) ((__attribute__((address_space(3))) unsigned int*)(p))

__device__ __forceinline__ u16 f2bf(float f) {
    union { float f; unsigned int i; } c; c.f = f;
    unsigned int u = c.i;
    return (u16)((u + 0x7FFFu + ((u >> 16) & 1u)) >> 16);   // RNE
}

__global__ void zero4(float4* __restrict__ p, long n4) {
    long i = (long)blockIdx.x * blockDim.x + threadIdx.x;
    long st = (long)gridDim.x * blockDim.x;
    float4 z = make_float4(0.f, 0.f, 0.f, 0.f);
    for (; i < n4; i += st) p[i] = z;
}

__global__ void count_edges(const int* __restrict__ etype, const int* __restrict__ dst,
                            float* __restrict__ cnt) {
    int e = blockIdx.x * blockDim.x + threadIdx.x;
    if (e < kE) atomicAdd(&cnt[etype[e] * kN + dst[e]], 1.0f);
}

__global__ void make_rscale(float* __restrict__ cnt) {
    int i = blockIdx.x * blockDim.x + threadIdx.x;
    if (i < kR * kN) cnt[i] = 1.0f / fmaxf(cnt[i], 1.0f);
}

// One block per edge; 256 threads x 4 floats = D=1024.
__global__ void scatter_edges(const float* __restrict__ x, const int* __restrict__ src,
                              const int* __restrict__ dst, const int* __restrict__ etype,
                              int rel, float* __restrict__ mean) {
    int e = blockIdx.x;
    if (etype[e] != rel) return;
    int s = src[e], t = dst[e];
    int d = threadIdx.x << 2;
    float4 v = *reinterpret_cast<const float4*>(x + (size_t)s * kD + d);
    float* mp = mean + (size_t)t * kD + d;
    atomicAdd(mp + 0, v.x);
    atomicAdd(mp + 1, v.y);
    atomicAdd(mp + 2, v.z);
    atomicAdd(mp + 3, v.w);
}

__global__ void cvt_bf16(const float* __restrict__ s, u16* __restrict__ d, long n4) {
    long i = (long)blockIdx.x * blockDim.x + threadIdx.x;
    long st = (long)gridDim.x * blockDim.x;
    for (; i < n4; i += st) {
        float4 v = reinterpret_cast<const float4*>(s)[i];
        ushort4 o;
        o.x = f2bf(v.x); o.y = f2bf(v.y); o.z = f2bf(v.z); o.w = f2bf(v.w);
        reinterpret_cast<ushort4*>(d)[i] = o;
    }
}

// mean fp32 -> bf16 with per-row 1/cnt scale. kD/4 = 256 float4 per row.
__global__ void cvt_bf16_scaled(const float* __restrict__ s, const float* __restrict__ rs,
                                u16* __restrict__ d, long n4) {
    long i = (long)blockIdx.x * blockDim.x + threadIdx.x;
    long st = (long)gridDim.x * blockDim.x;
    for (; i < n4; i += st) {
        float sc = rs[i >> 8];
        float4 v = reinterpret_cast<const float4*>(s)[i];
        ushort4 o;
        o.x = f2bf(v.x * sc); o.y = f2bf(v.y * sc);
        o.z = f2bf(v.z * sc); o.w = f2bf(v.w * sc);
        reinterpret_cast<ushort4*>(d)[i] = o;
    }
}

// S [rows][cols] fp32 -> D [cols][rows] bf16 (i.e. B -> B^T). rows,cols % 32 == 0.
// blockIdx.z batches matrices of size rows*cols.
__global__ void transpose_to_bf16(const float* __restrict__ S, u16* __restrict__ D,
                                  int rows, int cols) {
    S += (size_t)blockIdx.z * rows * cols;
    D += (size_t)blockIdx.z * rows * cols;
    __shared__ float t[32][33];
    int c0 = blockIdx.x * 32, r0 = blockIdx.y * 32;
    int x = threadIdx.x, y = threadIdx.y;   // block (32,8)
#pragma unroll
    for (int i = 0; i < 32; i += 8)
        t[y + i][x] = S[(size_t)(r0 + y + i) * cols + c0 + x];
    __syncthreads();
#pragma unroll
    for (int i = 0; i < 32; i += 8)
        D[(size_t)(c0 + y + i) * rows + r0 + x] = f2bf(t[x][y + i]);
}

// C[M,Ncols] (+)= A[M,K]bf16 @ Bt[Ncols,K]bf16^T (+ bias). fp32 accumulate in C.
// 128x128 tile, BK=32, 256 threads = 4 waves, each wave 64x64 (4x4 MFMA 16x16x32).
// A must be padded to >= gridDim.y*128 rows (reads are unguarded; C stores guarded).
__global__ __launch_bounds__(256) void gemm_mfma(
    const u16* __restrict__ A, int lda,
    const u16* __restrict__ Bt, int ldb,
    float* __restrict__ C, int M, int Ncols, int K,
    const float* __restrict__ bias, int accumulate)
{
    __shared__ u16 sA[128 * 32];
    __shared__ u16 sB[128 * 32];

    const int tid = threadIdx.x;
    const int wave = tid >> 6;
    const int lane = tid & 63;

    const int row0 = blockIdx.y * 128;
    const int col0 = blockIdx.x * 128;

    // staging: round p (0/1): row = p*64 + wave*16 + lane/4, 16B chunk lane%4
    const int srow = wave * 16 + (lane >> 2);
    const int scol = (lane & 3) * 8;   // element offset (8 bf16 = 16 B)

    const u16* gA0 = A + (size_t)(row0 + srow) * lda + scol;
    const u16* gA1 = A + (size_t)(row0 + 64 + srow) * lda + scol;
    const u16* gB0 = Bt + (size_t)(col0 + srow) * ldb + scol;
    const u16* gB1 = Bt + (size_t)(col0 + 64 + srow) * ldb + scol;

    u16* lA0 = sA + (wave * 16) * 32;        // + lane*16B implied by HW
    u16* lA1 = sA + (64 + wave * 16) * 32;
    u16* lB0 = sB + (wave * 16) * 32;
    u16* lB1 = sB + (64 + wave * 16) * 32;

    const int mq = (wave >> 1) * 64;   // wave's 64x64 quadrant
    const int nq = (wave & 1) * 64;
    const int fm = lane & 15;          // A/B frag: index within 16
    const int fk = (lane >> 4) * 8;    // A/B frag: k offset (8 contiguous)

    f32x4 zf = {0.0f, 0.0f, 0.0f, 0.0f};
    f32x4 acc[4][4];
#pragma unroll
    for (int i = 0; i < 4; ++i)
#pragma unroll
        for (int j = 0; j < 4; ++j) acc[i][j] = zf;

    for (int k0 = 0; k0 < K; k0 += 32) {
        __syncthreads();
        __builtin_amdgcn_global_load_lds(GLB(gA0), LDSP(lA0), 16, 0, 0);
        __builtin_amdgcn_global_load_lds(GLB(gA1), LDSP(lA1), 16, 0, 0);
        __builtin_amdgcn_global_load_lds(GLB(gB0), LDSP(lB0), 16, 0, 0);
        __builtin_amdgcn_global_load_lds(GLB(gB1), LDSP(lB1), 16, 0, 0);
        gA0 += 32; gA1 += 32; gB0 += 32; gB1 += 32;
        __syncthreads();

        bf16x8 af[4], bfr[4];
#pragma unroll
        for (int i = 0; i < 4; ++i)
            af[i] = *reinterpret_cast<const bf16x8*>(&sA[(mq + i * 16 + fm) * 32 + fk]);
#pragma unroll
        for (int j = 0; j < 4; ++j)
            bfr[j] = *reinterpret_cast<const bf16x8*>(&sB[(nq + j * 16 + fm) * 32 + fk]);
#pragma unroll
        for (int i = 0; i < 4; ++i)
#pragma unroll
            for (int j = 0; j < 4; ++j)
                acc[i][j] = __builtin_amdgcn_mfma_f32_16x16x32_bf16(af[i], bfr[j], acc[i][j], 0, 0, 0);
    }

    // C/D layout: col = lane&15, row = (lane>>4)*4 + reg
    const int lr = (lane >> 4) * 4;
    const int lc = lane & 15;
#pragma unroll
    for (int j = 0; j < 4; ++j) {
        int col = col0 + nq + j * 16 + lc;
        float bv = bias ? bias[col] : 0.0f;
#pragma unroll
        for (int i = 0; i < 4; ++i) {
            int rowb = row0 + mq + i * 16 + lr;
#pragma unroll
            for (int r = 0; r < 4; ++r) {
                int row = rowb + r;
                if (row < M) {
                    size_t off = (size_t)row * Ncols + col;
                    float v = acc[i][j][r] + bv;
                    if (accumulate) v += C[off];
                    C[off] = v;
                }
            }
        }
    }
}

__global__ void combine(const float* __restrict__ u, const float* __restrict__ z,
                        const float* __restrict__ x, float* __restrict__ out, long n) {
    long i = (long)blockIdx.x * blockDim.x + threadIdx.x;
    long stride = (long)gridDim.x * blockDim.x;
    for (; i < n; i += stride) {
        float uv = u[i];
        float zv = z[i];
        float xv = x[i];
        out[i] = tanhf(uv) * zv + xv * (1.0f - zv);
    }
}

extern "C" void kernel_launch(void* const* d_in, const int* in_sizes, int n_in,
                              void* d_out, int out_size, void* d_ws, size_t ws_size,
                              hipStream_t stream) {
    (void)in_sizes; (void)n_in; (void)out_size; (void)ws_size;

    const float* x     = (const float*)d_in[0];
    const int* eidx    = (const int*)d_in[1];
    const int* etype   = (const int*)d_in[2];
    const float* weight= (const float*)d_in[3];
    const float* root  = (const float*)d_in[4];
    const float* bias  = (const float*)d_in[5];
    const float* wgate = (const float*)d_in[6];
    const float* bgate = (const float*)d_in[7];
    float* out = (float*)d_out;

    const int* src = eidx;          // edge_index[0]
    const int* dst = eidx + kE;     // edge_index[1]

    // ---- workspace layout (bytes) ----
    char* ws = (char*)d_ws;
    size_t off = 0;
    float* u = (float*)(ws + off);        off += (size_t)kNpad * kD * 4;   // 41.4 MB
    float* mean = (float*)(ws + off);                                      // fp32 scatter buf
    u16* u_bf = (u16*)mean;               off += (size_t)kN * kD * 4;      // 41.0 MB (u_bf aliases mean; mean dead before u_bf written)
    float* cnt = (float*)(ws + off);      off += (size_t)kR * kN * 4;      // 0.3 MB
    u16* x_bf = (u16*)(ws + off);         off += (size_t)kNpad * kD * 2;   // 20.7 MB
    u16* mean_bf = (u16*)(ws + off);      off += (size_t)kNpad * kD * 2;   // 20.7 MB
    u16* wt = (u16*)(ws + off);           off += (size_t)kR * kD * kD * 2; // 16.8 MB
    u16* root_t = (u16*)(ws + off);       off += (size_t)kD * kD * 2;      // 2.1 MB
    u16* wgate_t = (u16*)(ws + off);      off += (size_t)2 * kD * kD * 2;  // 4.2 MB

    // counts -> 1/cnt
    zero4<<<64, 256, 0, stream>>>((float4*)cnt, (long)kR * kN / 4);
    count_edges<<<(kE + 255) / 256, 256, 0, stream>>>(etype, dst, cnt);
    make_rscale<<<(kR * kN + 255) / 256, 256, 0, stream>>>(cnt);

    // x -> bf16; weights -> transposed bf16
    cvt_bf16<<<2048, 256, 0, stream>>>(x, x_bf, (long)kN * kD / 4);
    {
        dim3 b(32, 8);
        transpose_to_bf16<<<dim3(kD / 32, kD / 32, kR), b, 0, stream>>>(weight, wt, kD, kD);
        transpose_to_bf16<<<dim3(kD / 32, kD / 32, 1), b, 0, stream>>>(root, root_t, kD, kD);
        transpose_to_bf16<<<dim3(kD / 32, 2 * kD / 32, 1), b, 0, stream>>>(wgate, wgate_t, 2 * kD, kD);
    }

    dim3 gg(kD / 128, kNpad / 128);   // 8 x 79

    // u = x @ root + bias
    gemm_mfma<<<gg, 256, 0, stream>>>(x_bf, kD, root_t, kD, u, kN, kD, kD, bias, 0);

    // u += mean_r @ W_r
    for (int r = 0; r < kR; ++r) {
        zero4<<<2048, 256, 0, stream>>>((float4*)mean, (long)kN * kD / 4);
        scatter_edges<<<kE, 256, 0, stream>>>(x, src, dst, etype, r, mean);
        cvt_bf16_scaled<<<2048, 256, 0, stream>>>(mean, cnt + (size_t)r * kN, mean_bf,
                                                  (long)kN * kD / 4);
        gemm_mfma<<<gg, 256, 0, stream>>>(mean_bf, kD, wt + (size_t)r * kD * kD, kD,
                                          u, kN, kD, kD, nullptr, 1);
    }

    // u -> bf16 (mean fp32 is dead now; u_bf aliases it)
    cvt_bf16<<<2048, 256, 0, stream>>>(u, u_bf, (long)kN * kD / 4);

    // z = u @ Wg_top + x @ Wg_bot + b_gate   (z lives in d_out)
    gemm_mfma<<<gg, 256, 0, stream>>>(u_bf, kD, wgate_t, 2 * kD, out, kN, kD, kD, bgate, 0);
    gemm_mfma<<<gg, 256, 0, stream>>>(x_bf, kD, wgate_t + kD, 2 * kD, out, kN, kD, kD, nullptr, 1);

    // h = tanh(u)*z + x*(1-z), in place over z
    combine<<<2048, 256, 0, stream>>>(u, out, x, out, (long)kN * kD);
}

// Round 4
// 694.705 us; speedup vs baseline: 7.4141x; 2.9949x over previous
//
#include <hip/hip_runtime.h>
#include <math.h>

typedef unsigned short u16;
typedef __attribute__((ext_vector_type(8))) short bf16x8;   // 8 bf16 = 4 VGPRs
typedef __attribute__((ext_vector_type(4))) float f32x4;

static constexpr int kN = 10000;
static constexpr int kNpad = 10112;       // 79 * 128
static constexpr int kD = 1024;
static constexpr int kR = 8;
static constexpr int kE = 80000;
static constexpr int kKu = kD * (kR + 1); // 9216 : [x | mean_0..mean_7]
static constexpr int kKz = 2 * kD;        // 2048 : [u | x]

#define GLB(p) ((const __attribute__((address_space(1))) unsigned int*)(const void*)(p))
#define LDSP(p) ((__attribute__((address_space(3))) unsigned int*)(p))

__device__ __forceinline__ u16 f2bf(float f) {
    union { float f; unsigned int i; } c; c.f = f;
    unsigned int u = c.i;
    return (u16)((u + 0x7FFFu + ((u >> 16) & 1u)) >> 16);   // RNE
}
__device__ __forceinline__ float bf2f(u16 u) {
    union { unsigned int i; float f; } c; c.i = ((unsigned int)u) << 16;
    return c.f;
}
__device__ __forceinline__ ushort4 f2bf4(float4 v) {
    ushort4 o; o.x = f2bf(v.x); o.y = f2bf(v.y); o.z = f2bf(v.z); o.w = f2bf(v.w);
    return o;
}

__global__ void zero16(uint4* __restrict__ p, long n16) {
    long i = (long)blockIdx.x * blockDim.x + threadIdx.x;
    long st = (long)gridDim.x * blockDim.x;
    uint4 z = make_uint4(0, 0, 0, 0);
    for (; i < n16; i += st) p[i] = z;
}

__global__ void hist_dst(const int* __restrict__ dst, int* __restrict__ cnt) {
    int e = blockIdx.x * blockDim.x + threadIdx.x;
    if (e < kE) atomicAdd(&cnt[dst[e]], 1);
}

// Single block, 1024 threads: exclusive scan of cnt[0..kN) -> rowptr[0..kN], zero cursor.
__global__ __launch_bounds__(1024) void scan_rowptr(const int* __restrict__ cnt,
                                                    int* __restrict__ rowptr,
                                                    int* __restrict__ cursor) {
    __shared__ int buf[1024];
    __shared__ int carry;
    const int tid = threadIdx.x;
    if (tid == 0) carry = 0;
    __syncthreads();
    const int nchunk = (kN + 1024) / 1024;   // covers idx == kN
    for (int ch = 0; ch < nchunk; ++ch) {
        int idx = ch * 1024 + tid;
        int v = (idx < kN) ? cnt[idx] : 0;
        buf[tid] = v;
        __syncthreads();
        for (int off = 1; off < 1024; off <<= 1) {
            int t = (tid >= off) ? buf[tid - off] : 0;
            __syncthreads();
            buf[tid] += t;
            __syncthreads();
        }
        int excl = buf[tid] - v + carry;
        if (idx <= kN) rowptr[idx] = excl;
        if (idx < kN) cursor[idx] = 0;
        __syncthreads();
        if (tid == 1023) carry += buf[1023];
        __syncthreads();
    }
}

__global__ void fill_edges(const int* __restrict__ src, const int* __restrict__ dst,
                           const int* __restrict__ etype, const int* __restrict__ rowptr,
                           int* __restrict__ cursor, int* __restrict__ erec) {
    int e = blockIdx.x * blockDim.x + threadIdx.x;
    if (e < kE) {
        int d = dst[e];
        int pos = rowptr[d] + atomicAdd(&cursor[d], 1);
        erec[pos] = (src[e] << 3) | etype[e];
    }
}

// x fp32 -> bf16 into Abig[:,0:1024] (ld kKu) and ga[:,1024:2048] (ld kKz).
__global__ void cvt_x(const float* __restrict__ x, u16* __restrict__ Abig,
                      u16* __restrict__ ga) {
    int row = blockIdx.x;
    int c = threadIdx.x << 2;
    float4 v = *reinterpret_cast<const float4*>(x + (size_t)row * kD + c);
    ushort4 o = f2bf4(v);
    *reinterpret_cast<ushort4*>(Abig + (size_t)row * kKu + c) = o;
    *reinterpret_cast<ushort4*>(ga + (size_t)row * kKz + kD + c) = o;
}

// S [rows][cols] fp32 -> D[c*ldD + koff_base + z*rows + r] bf16 (B -> B^T stacked along K).
__global__ void transpose_to_bf16(const float* __restrict__ S, u16* __restrict__ D,
                                  int rows, int cols, int ldD, int koff_base) {
    S += (size_t)blockIdx.z * rows * cols;
    const int koff = koff_base + blockIdx.z * rows;
    __shared__ float t[32][33];
    int c0 = blockIdx.x * 32, r0 = blockIdx.y * 32;
    int x = threadIdx.x, y = threadIdx.y;   // block (32,8)
#pragma unroll
    for (int i = 0; i < 32; i += 8)
        t[y + i][x] = S[(size_t)(r0 + y + i) * cols + c0 + x];
    __syncthreads();
#pragma unroll
    for (int i = 0; i < 32; i += 8)
        D[(size_t)(c0 + y + i) * ldD + koff + r0 + x] = f2bf(t[x][y + i]);
}

#define ACC_CASE(r) case r: acc##r.x += v.x; acc##r.y += v.y; acc##r.z += v.z; acc##r.w += v.w; c##r++; break;
#define EMIT(r) { float s = 1.0f / fmaxf((float)c##r, 1.0f); \
    float4 m = make_float4(acc##r.x * s, acc##r.y * s, acc##r.z * s, acc##r.w * s); \
    *reinterpret_cast<ushort4*>(ap + (size_t)(r + 1) * kD) = f2bf4(m); }

// One block (256 thr) per dst row: gather x[src], accumulate 8 relation means,
// write bf16 into Abig[:,1024:9216].
__global__ __launch_bounds__(256) void aggregate(const float* __restrict__ x,
                                                 const int* __restrict__ rowptr,
                                                 const int* __restrict__ erec,
                                                 u16* __restrict__ Abig) {
    const int d = blockIdx.x;
    const int c = threadIdx.x << 2;
    const int e0 = rowptr[d], e1 = rowptr[d + 1];
    float4 acc0 = {0,0,0,0}, acc1 = {0,0,0,0}, acc2 = {0,0,0,0}, acc3 = {0,0,0,0};
    float4 acc4 = {0,0,0,0}, acc5 = {0,0,0,0}, acc6 = {0,0,0,0}, acc7 = {0,0,0,0};
    int c0 = 0, c1 = 0, c2 = 0, c3 = 0, c4 = 0, c5 = 0, c6 = 0, c7 = 0;
    for (int e = e0; e < e1; ++e) {
        int rec = erec[e];                 // uniform across block
        int rel = rec & 7;
        int s = rec >> 3;
        float4 v = *reinterpret_cast<const float4*>(x + (size_t)s * kD + c);
        switch (rel) {
            ACC_CASE(0) ACC_CASE(1) ACC_CASE(2) ACC_CASE(3)
            ACC_CASE(4) ACC_CASE(5) ACC_CASE(6) ACC_CASE(7)
        }
    }
    u16* ap = Abig + (size_t)d * kKu + c;
    EMIT(0) EMIT(1) EMIT(2) EMIT(3) EMIT(4) EMIT(5) EMIT(6) EMIT(7)
}

// C = A[M,K]bf16 @ Bt[Ncols,K]bf16^T (+bias). 128x128 tile, BK=32, 4 waves.
// MODE 0: store f2bf(acc+bias) into Cbf (ld ldc)      [u-GEMM -> ga[:,0:1024]]
// MODE 1: z=acc+bias; h=tanh(u)*z + x*(1-z) -> Cf     [z-GEMM + combine]
template <int MODE>
__global__ __launch_bounds__(256) void gemm_mfma(
    const u16* __restrict__ A, int lda,
    const u16* __restrict__ Bt, int ldb, int K,
    int M, int Ncols, const float* __restrict__ bias,
    u16* __restrict__ Cbf, int ldc,
    float* __restrict__ Cf, const u16* __restrict__ uga, const float* __restrict__ xo)
{
    __shared__ u16 sA[128 * 32];
    __shared__ u16 sB[128 * 32];

    const int tid = threadIdx.x;
    const int wave = tid >> 6;
    const int lane = tid & 63;

    const int row0 = blockIdx.y * 128;
    const int col0 = blockIdx.x * 128;

    const int srow = wave * 16 + (lane >> 2);
    const int scol = (lane & 3) * 8;

    const u16* gA0 = A + (size_t)(row0 + srow) * lda + scol;
    const u16* gA1 = A + (size_t)(row0 + 64 + srow) * lda + scol;
    const u16* gB0 = Bt + (size_t)(col0 + srow) * ldb + scol;
    const u16* gB1 = Bt + (size_t)(col0 + 64 + srow) * ldb + scol;

    u16* lA0 = sA + (wave * 16) * 32;
    u16* lA1 = sA + (64 + wave * 16) * 32;
    u16* lB0 = sB + (wave * 16) * 32;
    u16* lB1 = sB + (64 + wave * 16) * 32;

    const int mq = (wave >> 1) * 64;
    const int nq = (wave & 1) * 64;
    const int fm = lane & 15;
    const int fk = (lane >> 4) * 8;

    f32x4 zf = {0.0f, 0.0f, 0.0f, 0.0f};
    f32x4 acc[4][4];
#pragma unroll
    for (int i = 0; i < 4; ++i)
#pragma unroll
        for (int j = 0; j < 4; ++j) acc[i][j] = zf;

    for (int k0 = 0; k0 < K; k0 += 32) {
        __syncthreads();
        __builtin_amdgcn_global_load_lds(GLB(gA0), LDSP(lA0), 16, 0, 0);
        __builtin_amdgcn_global_load_lds(GLB(gA1), LDSP(lA1), 16, 0, 0);
        __builtin_amdgcn_global_load_lds(GLB(gB0), LDSP(lB0), 16, 0, 0);
        __builtin_amdgcn_global_load_lds(GLB(gB1), LDSP(lB1), 16, 0, 0);
        gA0 += 32; gA1 += 32; gB0 += 32; gB1 += 32;
        __syncthreads();

        bf16x8 af[4], bfr[4];
#pragma unroll
        for (int i = 0; i < 4; ++i)
            af[i] = *reinterpret_cast<const bf16x8*>(&sA[(mq + i * 16 + fm) * 32 + fk]);
#pragma unroll
        for (int j = 0; j < 4; ++j)
            bfr[j] = *reinterpret_cast<const bf16x8*>(&sB[(nq + j * 16 + fm) * 32 + fk]);
#pragma unroll
        for (int i = 0; i < 4; ++i)
#pragma unroll
            for (int j = 0; j < 4; ++j)
                acc[i][j] = __builtin_amdgcn_mfma_f32_16x16x32_bf16(af[i], bfr[j], acc[i][j], 0, 0, 0);
    }

    // C/D layout: col = lane&15, row = (lane>>4)*4 + reg
    const int lr = (lane >> 4) * 4;
    const int lc = lane & 15;
#pragma unroll
    for (int j = 0; j < 4; ++j) {
        int col = col0 + nq + j * 16 + lc;
        float bv = bias ? bias[col] : 0.0f;
#pragma unroll
        for (int i = 0; i < 4; ++i) {
            int rowb = row0 + mq + i * 16 + lr;
#pragma unroll
            for (int r = 0; r < 4; ++r) {
                int row = rowb + r;
                if (row < M) {
                    float v = acc[i][j][r] + bv;
                    if (MODE == 0) {
                        Cbf[(size_t)row * ldc + col] = f2bf(v);
                    } else {
                        float uv = bf2f(uga[(size_t)row * kKz + col]);
                        float xv = xo[(size_t)row * kD + col];
                        Cf[(size_t)row * kD + col] = tanhf(uv) * v + xv * (1.0f - v);
                    }
                }
            }
        }
    }
}

extern "C" void kernel_launch(void* const* d_in, const int* in_sizes, int n_in,
                              void* d_out, int out_size, void* d_ws, size_t ws_size,
                              hipStream_t stream) {
    (void)in_sizes; (void)n_in; (void)out_size; (void)ws_size;

    const float* x     = (const float*)d_in[0];
    const int* eidx    = (const int*)d_in[1];
    const int* etype   = (const int*)d_in[2];
    const float* weight= (const float*)d_in[3];
    const float* root  = (const float*)d_in[4];
    const float* bias  = (const float*)d_in[5];
    const float* wgate = (const float*)d_in[6];
    const float* bgate = (const float*)d_in[7];
    float* out = (float*)d_out;

    const int* src = eidx;
    const int* dst = eidx + kE;

    // ---- workspace ----
    char* ws = (char*)d_ws;
    size_t off = 0;
    u16* Abig = (u16*)(ws + off);    off += (size_t)kNpad * kKu * 2;  // 186.4 MB
    u16* ga   = (u16*)(ws + off);    off += (size_t)kNpad * kKz * 2;  //  41.4 MB
    u16* Bf   = (u16*)(ws + off);    off += (size_t)kD * kKu * 2;     //  18.9 MB
    u16* wg_t = (u16*)(ws + off);    off += (size_t)kD * kKz * 2;     //   4.2 MB
    int* cntd = (int*)(ws + off);    off += (size_t)kN * 4;
    int* rowp = (int*)(ws + off);    off += (size_t)(kN + 16) * 4;
    int* curs = (int*)(ws + off);    off += (size_t)kN * 4;
    int* erec = (int*)(ws + off);    off += (size_t)kE * 4;

    // CSR by dst
    zero16<<<16, 256, 0, stream>>>((uint4*)cntd, (long)kN * 4 / 16);
    hist_dst<<<(kE + 255) / 256, 256, 0, stream>>>(dst, cntd);
    scan_rowptr<<<1, 1024, 0, stream>>>(cntd, rowp, curs);
    fill_edges<<<(kE + 255) / 256, 256, 0, stream>>>(src, dst, etype, rowp, curs, erec);

    // zero padding rows [kN, kNpad) of Abig and ga (GEMM reads them unguarded)
    zero16<<<512, 256, 0, stream>>>((uint4*)(Abig + (size_t)kN * kKu),
                                    (long)(kNpad - kN) * kKu * 2 / 16);
    zero16<<<128, 256, 0, stream>>>((uint4*)(ga + (size_t)kN * kKz),
                                    (long)(kNpad - kN) * kKz * 2 / 16);

    // x -> bf16 (Abig col 0:1024, ga col 1024:2048)
    cvt_x<<<kN, 256, 0, stream>>>(x, Abig, ga);

    // weights -> transposed bf16, stacked along K
    {
        dim3 b(32, 8);
        transpose_to_bf16<<<dim3(kD / 32, kD / 32, 1), b, 0, stream>>>(root, Bf, kD, kD, kKu, 0);
        transpose_to_bf16<<<dim3(kD / 32, kD / 32, kR), b, 0, stream>>>(weight, Bf, kD, kD, kKu, kD);
        transpose_to_bf16<<<dim3(kD / 32, kKz / 32, 1), b, 0, stream>>>(wgate, wg_t, kKz, kD, kKz, 0);
    }

    // per-dst gather/mean -> Abig[:,1024:9216]
    aggregate<<<kN, 256, 0, stream>>>(x, rowp, erec, Abig);

    dim3 gg(kD / 128, kNpad / 128);   // 8 x 79

    // u = Abig @ Bf + bias  -> ga[:,0:1024] (bf16)
    gemm_mfma<0><<<gg, 256, 0, stream>>>(Abig, kKu, Bf, kKu, kKu, kN, kD, bias,
                                         ga, kKz, nullptr, nullptr, nullptr);

    // z = ga @ wg_t + b_gate;  h = tanh(u)*z + x*(1-z) -> out
    gemm_mfma<1><<<gg, 256, 0, stream>>>(ga, kKz, wg_t, kKz, kKz, kN, kD, bgate,
                                         nullptr, 0, out, ga, x);
}

// Round 5
// 629.177 us; speedup vs baseline: 8.1863x; 1.1041x over previous
//
#include <hip/hip_runtime.h>
#include <math.h>

typedef unsigned short u16;
typedef __attribute__((ext_vector_type(8))) short bf16x8;   // 8 bf16 = 4 VGPRs
typedef __attribute__((ext_vector_type(4))) float f32x4;

static constexpr int kN = 10000;
static constexpr int kNpad = 10112;       // 79 * 128
static constexpr int kD = 1024;
static constexpr int kR = 8;
static constexpr int kE = 80000;
static constexpr int kKy = kD * (kR + 1); // 9216 : y = x @ [root | W_0..W_7]
static constexpr int kKz = 2 * kD;        // 2048 : [u | x]

#define GLB(p) ((const __attribute__((address_space(1))) unsigned int*)(const void*)(p))
#define LDSP(p) ((__attribute__((address_space(3))) unsigned int*)(p))

__device__ __forceinline__ u16 f2bf(float f) {
    union { float f; unsigned int i; } c; c.f = f;
    unsigned int u = c.i;
    return (u16)((u + 0x7FFFu + ((u >> 16) & 1u)) >> 16);   // RNE
}
__device__ __forceinline__ float bf2f(u16 u) {
    union { unsigned int i; float f; } c; c.i = ((unsigned int)u) << 16;
    return c.f;
}
__device__ __forceinline__ ushort4 f2bf4(float4 v) {
    ushort4 o; o.x = f2bf(v.x); o.y = f2bf(v.y); o.z = f2bf(v.z); o.w = f2bf(v.w);
    return o;
}

__global__ void zero16(uint4* __restrict__ p, long n16) {
    long i = (long)blockIdx.x * blockDim.x + threadIdx.x;
    long st = (long)gridDim.x * blockDim.x;
    uint4 z = make_uint4(0, 0, 0, 0);
    for (; i < n16; i += st) p[i] = z;
}

__global__ void hist_dst(const int* __restrict__ dst, int* __restrict__ cnt) {
    int e = blockIdx.x * blockDim.x + threadIdx.x;
    if (e < kE) atomicAdd(&cnt[dst[e]], 1);
}

// Single block, 1024 threads: exclusive scan of cnt[0..kN) -> rowptr[0..kN], zero cursor.
__global__ __launch_bounds__(1024) void scan_rowptr(const int* __restrict__ cnt,
                                                    int* __restrict__ rowptr,
                                                    int* __restrict__ cursor) {
    __shared__ int buf[1024];
    __shared__ int carry;
    const int tid = threadIdx.x;
    if (tid == 0) carry = 0;
    __syncthreads();
    const int nchunk = (kN + 1024) / 1024;   // covers idx == kN
    for (int ch = 0; ch < nchunk; ++ch) {
        int idx = ch * 1024 + tid;
        int v = (idx < kN) ? cnt[idx] : 0;
        buf[tid] = v;
        __syncthreads();
        for (int off = 1; off < 1024; off <<= 1) {
            int t = (tid >= off) ? buf[tid - off] : 0;
            __syncthreads();
            buf[tid] += t;
            __syncthreads();
        }
        int excl = buf[tid] - v + carry;
        if (idx <= kN) rowptr[idx] = excl;
        if (idx < kN) cursor[idx] = 0;
        __syncthreads();
        if (tid == 1023) carry += buf[1023];
        __syncthreads();
    }
}

__global__ void fill_edges(const int* __restrict__ src, const int* __restrict__ dst,
                           const int* __restrict__ etype, const int* __restrict__ rowptr,
                           int* __restrict__ cursor, int* __restrict__ erec) {
    int e = blockIdx.x * blockDim.x + threadIdx.x;
    if (e < kE) {
        int d = dst[e];
        int pos = rowptr[d] + atomicAdd(&cursor[d], 1);
        erec[pos] = (src[e] << 3) | etype[e];
    }
}

// x fp32 -> bf16 into ga[:,1024:2048].
__global__ void cvt_x(const float* __restrict__ x, u16* __restrict__ ga) {
    int row = blockIdx.x;
    int c = threadIdx.x << 2;
    float4 v = *reinterpret_cast<const float4*>(x + (size_t)row * kD + c);
    *reinterpret_cast<ushort4*>(ga + (size_t)row * kKz + kD + c) = f2bf4(v);
}

// S [rows][cols] fp32 -> D[n*ldD + k] = S[k, n] bf16. Batched: S += z*rows*cols,
// D += z*rows*cols (square batches).
__global__ void transpose_to_bf16(const float* __restrict__ S, u16* __restrict__ D,
                                  int rows, int cols, int ldD) {
    S += (size_t)blockIdx.z * rows * cols;
    D += (size_t)blockIdx.z * rows * cols;
    __shared__ float t[32][33];
    int c0 = blockIdx.x * 32, r0 = blockIdx.y * 32;
    int x = threadIdx.x, y = threadIdx.y;   // block (32,8)
#pragma unroll
    for (int i = 0; i < 32; i += 8)
        t[y + i][x] = S[(size_t)(r0 + y + i) * cols + c0 + x];
    __syncthreads();
#pragma unroll
    for (int i = 0; i < 32; i += 8)
        D[(size_t)(c0 + y + i) * ldD + r0 + x] = f2bf(t[x][y + i]);
}

// One block (256 thr) per dst row: u[d] = y[d,root] + bias + sum_e rs[rel]*y[src,rel].
// Writes u bf16 into ga[:,0:1024].
__global__ __launch_bounds__(256) void aggregate(const u16* __restrict__ y,
                                                 const float* __restrict__ bias,
                                                 const int* __restrict__ rowptr,
                                                 const int* __restrict__ erec,
                                                 u16* __restrict__ ga) {
    const int d = blockIdx.x;
    const int c = threadIdx.x << 2;
    const int e0 = rowptr[d], e1 = rowptr[d + 1];

    __shared__ float rs[kR];
    if (threadIdx.x == 0) {
        int cc[kR] = {0, 0, 0, 0, 0, 0, 0, 0};
        for (int e = e0; e < e1; ++e) cc[erec[e] & 7]++;
#pragma unroll
        for (int r = 0; r < kR; ++r) rs[r] = 1.0f / fmaxf((float)cc[r], 1.0f);
    }
    __syncthreads();

    ushort4 rv = *reinterpret_cast<const ushort4*>(y + (size_t)d * kKy + c);
    float4 bv = *reinterpret_cast<const float4*>(bias + c);
    float4 acc = make_float4(bf2f(rv.x) + bv.x, bf2f(rv.y) + bv.y,
                             bf2f(rv.z) + bv.z, bf2f(rv.w) + bv.w);

    for (int e = e0; e < e1; ++e) {
        int rec = erec[e];              // uniform across block
        int rel = rec & 7;
        int s = rec >> 3;
        float sc = rs[rel];             // LDS broadcast
        ushort4 v = *reinterpret_cast<const ushort4*>(
            y + (size_t)s * kKy + ((rel + 1) << 10) + c);
        acc.x += sc * bf2f(v.x); acc.y += sc * bf2f(v.y);
        acc.z += sc * bf2f(v.z); acc.w += sc * bf2f(v.w);
    }
    *reinterpret_cast<ushort4*>(ga + (size_t)d * kKz + c) = f2bf4(acc);
}

// C = A[M,K]bf16 @ Bt[Ncols,K]bf16^T (+bias). 128x128 tile, BK=32, 4 waves.
// XOR-swizzled LDS staging: lane loads global chunk (lane&3)^(row&3), reader
// fetches chunk q^(row&3) -> 4-way max bank aliasing instead of 8-way.
// MODE 0: store f2bf(acc+bias) into Cbf (ld ldc)
// MODE 1: z=acc+bias; h=tanh(u)*z + x*(1-z) -> Cf
template <int MODE>
__global__ __launch_bounds__(256) void gemm_mfma(
    const u16* __restrict__ A, int lda,
    const u16* __restrict__ Bt, int ldb, int K,
    int M, int Ncols, const float* __restrict__ bias,
    u16* __restrict__ Cbf, int ldc,
    float* __restrict__ Cf, const u16* __restrict__ uga, const float* __restrict__ xo)
{
    __shared__ u16 sA[128 * 32];
    __shared__ u16 sB[128 * 32];

    const int tid = threadIdx.x;
    const int wave = tid >> 6;
    const int lane = tid & 63;

    const int row0 = blockIdx.y * 128;
    const int col0 = blockIdx.x * 128;

    const int srow = wave * 16 + (lane >> 2);
    const int scol = (((lane & 3) ^ (srow & 3)) << 3);   // swizzled 8-elem chunk

    const u16* gA0 = A + (size_t)(row0 + srow) * lda + scol;
    const u16* gA1 = A + (size_t)(row0 + 64 + srow) * lda + scol;
    const u16* gB0 = Bt + (size_t)(col0 + srow) * ldb + scol;
    const u16* gB1 = Bt + (size_t)(col0 + 64 + srow) * ldb + scol;

    u16* lA0 = sA + (wave * 16) * 32;
    u16* lA1 = sA + (64 + wave * 16) * 32;
    u16* lB0 = sB + (wave * 16) * 32;
    u16* lB1 = sB + (64 + wave * 16) * 32;

    const int mq = (wave >> 1) * 64;
    const int nq = (wave & 1) * 64;
    const int fm = lane & 15;
    const int fq = (lane >> 4);                 // logical k-chunk 0..3
    const int fko = ((fq ^ (fm & 3)) << 3);     // swizzled element offset in LDS row

    f32x4 zf = {0.0f, 0.0f, 0.0f, 0.0f};
    f32x4 acc[4][4];
#pragma unroll
    for (int i = 0; i < 4; ++i)
#pragma unroll
        for (int j = 0; j < 4; ++j) acc[i][j] = zf;

    for (int k0 = 0; k0 < K; k0 += 32) {
        __syncthreads();
        __builtin_amdgcn_global_load_lds(GLB(gA0), LDSP(lA0), 16, 0, 0);
        __builtin_amdgcn_global_load_lds(GLB(gA1), LDSP(lA1), 16, 0, 0);
        __builtin_amdgcn_global_load_lds(GLB(gB0), LDSP(lB0), 16, 0, 0);
        __builtin_amdgcn_global_load_lds(GLB(gB1), LDSP(lB1), 16, 0, 0);
        gA0 += 32; gA1 += 32; gB0 += 32; gB1 += 32;
        __syncthreads();

        bf16x8 af[4], bfr[4];
#pragma unroll
        for (int i = 0; i < 4; ++i)
            af[i] = *reinterpret_cast<const bf16x8*>(&sA[(mq + i * 16 + fm) * 32 + fko]);
#pragma unroll
        for (int j = 0; j < 4; ++j)
            bfr[j] = *reinterpret_cast<const bf16x8*>(&sB[(nq + j * 16 + fm) * 32 + fko]);
#pragma unroll
        for (int i = 0; i < 4; ++i)
#pragma unroll
            for (int j = 0; j < 4; ++j)
                acc[i][j] = __builtin_amdgcn_mfma_f32_16x16x32_bf16(af[i], bfr[j], acc[i][j], 0, 0, 0);
    }

    // C/D layout: col = lane&15, row = (lane>>4)*4 + reg
    const int lr = (lane >> 4) * 4;
    const int lc = lane & 15;
#pragma unroll
    for (int j = 0; j < 4; ++j) {
        int col = col0 + nq + j * 16 + lc;
        float bv = bias ? bias[col] : 0.0f;
#pragma unroll
        for (int i = 0; i < 4; ++i) {
            int rowb = row0 + mq + i * 16 + lr;
#pragma unroll
            for (int r = 0; r < 4; ++r) {
                int row = rowb + r;
                if (row < M) {
                    float v = acc[i][j][r] + bv;
                    if (MODE == 0) {
                        Cbf[(size_t)row * ldc + col] = f2bf(v);
                    } else {
                        float uv = bf2f(uga[(size_t)row * kKz + col]);
                        float xv = xo[(size_t)row * kD + col];
                        Cf[(size_t)row * kD + col] = tanhf(uv) * v + xv * (1.0f - v);
                    }
                }
            }
        }
    }
}

extern "C" void kernel_launch(void* const* d_in, const int* in_sizes, int n_in,
                              void* d_out, int out_size, void* d_ws, size_t ws_size,
                              hipStream_t stream) {
    (void)in_sizes; (void)n_in; (void)out_size; (void)ws_size;

    const float* x     = (const float*)d_in[0];
    const int* eidx    = (const int*)d_in[1];
    const int* etype   = (const int*)d_in[2];
    const float* weight= (const float*)d_in[3];
    const float* root  = (const float*)d_in[4];
    const float* bias  = (const float*)d_in[5];
    const float* wgate = (const float*)d_in[6];
    const float* bgate = (const float*)d_in[7];
    float* out = (float*)d_out;

    const int* src = eidx;
    const int* dst = eidx + kE;

    // ---- workspace ----
    char* ws = (char*)d_ws;
    size_t off = 0;
    u16* y    = (u16*)(ws + off);    off += (size_t)kNpad * kKy * 2;  // 186.4 MB
    u16* ga   = (u16*)(ws + off);    off += (size_t)kNpad * kKz * 2;  //  41.4 MB
    u16* Bt9  = (u16*)(ws + off);    off += (size_t)kKy * kD * 2;     //  18.9 MB
    u16* wg_t = (u16*)(ws + off);    off += (size_t)kD * kKz * 2;     //   4.2 MB
    int* cntd = (int*)(ws + off);    off += (size_t)kN * 4;
    int* rowp = (int*)(ws + off);    off += (size_t)(kN + 16) * 4;
    int* curs = (int*)(ws + off);    off += (size_t)kN * 4;
    int* erec = (int*)(ws + off);    off += (size_t)kE * 4;

    // CSR by dst
    zero16<<<16, 256, 0, stream>>>((uint4*)cntd, (long)kN * 4 / 16);
    hist_dst<<<(kE + 255) / 256, 256, 0, stream>>>(dst, cntd);
    scan_rowptr<<<1, 1024, 0, stream>>>(cntd, rowp, curs);
    fill_edges<<<(kE + 255) / 256, 256, 0, stream>>>(src, dst, etype, rowp, curs, erec);

    // zero padding rows [kN, kNpad) of ga (GEMMs read A rows unguarded)
    zero16<<<128, 256, 0, stream>>>((uint4*)(ga + (size_t)kN * kKz),
                                    (long)(kNpad - kN) * kKz * 2 / 16);

    // x -> bf16 into ga[:,1024:2048]
    cvt_x<<<kN, 256, 0, stream>>>(x, ga);

    // Bt9[n,k]: n in [0,1024) root^T; n in [1024(1+r), ...) W_r^T. wg_t[n,k]=wgate[k,n].
    {
        dim3 b(32, 8);
        transpose_to_bf16<<<dim3(kD / 32, kD / 32, 1), b, 0, stream>>>(root, Bt9, kD, kD, kD);
        transpose_to_bf16<<<dim3(kD / 32, kD / 32, kR), b, 0, stream>>>(
            weight, Bt9 + (size_t)kD * kD, kD, kD, kD);
        transpose_to_bf16<<<dim3(kD / 32, kKz / 32, 1), b, 0, stream>>>(wgate, wg_t, kKz, kD, kKz);
    }

    // GEMM1: y = [x] @ [root|W_0..W_7]  (A = x slice of ga, lda=2048)
    dim3 g1(kKy / 128, kNpad / 128);   // 72 x 79
    gemm_mfma<0><<<g1, 256, 0, stream>>>(ga + kD, kKz, Bt9, kD, kD, kN, kKy, nullptr,
                                         y, kKy, nullptr, nullptr, nullptr);

    // aggregate: u -> ga[:,0:1024] (bf16)
    aggregate<<<kN, 256, 0, stream>>>(y, bias, rowp, erec, ga);

    // GEMM2: z = ga @ wg_t + b_gate; h = tanh(u)*z + x*(1-z) -> out
    dim3 g2(kD / 128, kNpad / 128);    // 8 x 79
    gemm_mfma<1><<<g2, 256, 0, stream>>>(ga, kKz, wg_t, kKz, kKz, kN, kD, bgate,
                                         nullptr, 0, out, ga, x);
}

// Round 6
// 583.648 us; speedup vs baseline: 8.8249x; 1.0780x over previous
//
#include <hip/hip_runtime.h>
#include <math.h>

typedef unsigned short u16;
typedef __attribute__((ext_vector_type(8))) short bf16x8;   // 8 bf16 = 4 VGPRs
typedef __attribute__((ext_vector_type(4))) float f32x4;

static constexpr int kN = 10000;
static constexpr int kNpad = 10112;       // 79 * 128
static constexpr int kD = 1024;
static constexpr int kR = 8;
static constexpr int kE = 80000;
static constexpr int kKy = kD * (kR + 1); // 9216 : y = x @ [root | W_0..W_7]
static constexpr int kKz = 2 * kD;        // 2048 : [u | x]

#define GLB(p) ((const __attribute__((address_space(1))) unsigned int*)(const void*)(p))
#define LDSP(p) ((__attribute__((address_space(3))) unsigned int*)(p))

__device__ __forceinline__ u16 f2bf(float f) {
    union { float f; unsigned int i; } c; c.f = f;
    unsigned int u = c.i;
    return (u16)((u + 0x7FFFu + ((u >> 16) & 1u)) >> 16);   // RNE
}
__device__ __forceinline__ float bf2f(u16 u) {
    union { unsigned int i; float f; } c; c.i = ((unsigned int)u) << 16;
    return c.f;
}
__device__ __forceinline__ ushort4 f2bf4(float4 v) {
    ushort4 o; o.x = f2bf(v.x); o.y = f2bf(v.y); o.z = f2bf(v.z); o.w = f2bf(v.w);
    return o;
}

__global__ void zero16(uint4* __restrict__ p, long n16) {
    long i = (long)blockIdx.x * blockDim.x + threadIdx.x;
    long st = (long)gridDim.x * blockDim.x;
    uint4 z = make_uint4(0, 0, 0, 0);
    for (; i < n16; i += st) p[i] = z;
}

__global__ void hist_dst(const int* __restrict__ dst, int* __restrict__ cnt) {
    int e = blockIdx.x * blockDim.x + threadIdx.x;
    if (e < kE) atomicAdd(&cnt[dst[e]], 1);
}

// Single block, 1024 threads: exclusive scan of cnt[0..kN) -> rowptr[0..kN], zero cursor.
// Wave-shuffle scan: 2 barriers per 1024-chunk (was 20).
__global__ __launch_bounds__(1024) void scan_rowptr(const int* __restrict__ cnt,
                                                    int* __restrict__ rowptr,
                                                    int* __restrict__ cursor) {
    __shared__ int wsum[16];
    __shared__ int carry;
    const int tid = threadIdx.x;
    const int lane = tid & 63;
    const int w = tid >> 6;
    if (tid == 0) carry = 0;
    const int nchunk = (kN + 1024) / 1024;
    for (int ch = 0; ch < nchunk; ++ch) {
        int idx = ch * 1024 + tid;
        int v = (idx < kN) ? cnt[idx] : 0;
        int s = v;
#pragma unroll
        for (int off = 1; off < 64; off <<= 1) {
            int t = __shfl_up(s, off, 64);
            if (lane >= off) s += t;
        }
        if (lane == 63) wsum[w] = s;
        __syncthreads();
        if (w == 0 && lane < 16) {
            int t = wsum[lane];
#pragma unroll
            for (int off = 1; off < 16; off <<= 1) {
                int tt = __shfl_up(t, off, 64);
                if (lane >= off) t += tt;
            }
            wsum[lane] = t;
        }
        __syncthreads();
        int wpre = (w > 0) ? wsum[w - 1] : 0;
        int incl = s + wpre + carry;
        int excl = incl - v;
        if (idx <= kN) rowptr[idx] = excl;
        if (idx < kN) cursor[idx] = 0;
        __syncthreads();
        if (tid == 1023) carry = incl;
        __syncthreads();
    }
}

__global__ void fill_edges(const int* __restrict__ src, const int* __restrict__ dst,
                           const int* __restrict__ etype, const int* __restrict__ rowptr,
                           int* __restrict__ cursor, int* __restrict__ erec) {
    int e = blockIdx.x * blockDim.x + threadIdx.x;
    if (e < kE) {
        int d = dst[e];
        int pos = rowptr[d] + atomicAdd(&cursor[d], 1);
        erec[pos] = (src[e] << 3) | etype[e];
    }
}

// x fp32 -> bf16 into ga[:,1024:2048].
__global__ void cvt_x(const float* __restrict__ x, u16* __restrict__ ga) {
    int row = blockIdx.x;
    int c = threadIdx.x << 2;
    float4 v = *reinterpret_cast<const float4*>(x + (size_t)row * kD + c);
    *reinterpret_cast<ushort4*>(ga + (size_t)row * kKz + kD + c) = f2bf4(v);
}

// S [rows][cols] fp32 -> D[n*ldD + k] = S[k, n] bf16. Batched square blocks.
__global__ void transpose_to_bf16(const float* __restrict__ S, u16* __restrict__ D,
                                  int rows, int cols, int ldD) {
    S += (size_t)blockIdx.z * rows * cols;
    D += (size_t)blockIdx.z * rows * cols;
    __shared__ float t[32][33];
    int c0 = blockIdx.x * 32, r0 = blockIdx.y * 32;
    int x = threadIdx.x, y = threadIdx.y;   // block (32,8)
#pragma unroll
    for (int i = 0; i < 32; i += 8)
        t[y + i][x] = S[(size_t)(r0 + y + i) * cols + c0 + x];
    __syncthreads();
#pragma unroll
    for (int i = 0; i < 32; i += 8)
        D[(size_t)(c0 + y + i) * ldD + r0 + x] = f2bf(t[x][y + i]);
}

// One block (256 thr) per dst row: u[d] = y[d,root] + bias + sum_e rs[rel]*y[src,rel].
// Writes u bf16 into ga[:,0:1024].
__global__ __launch_bounds__(256) void aggregate(const u16* __restrict__ y,
                                                 const float* __restrict__ bias,
                                                 const int* __restrict__ rowptr,
                                                 const int* __restrict__ erec,
                                                 u16* __restrict__ ga) {
    const int d = blockIdx.x;
    const int c = threadIdx.x << 2;
    const int e0 = rowptr[d], e1 = rowptr[d + 1];

    __shared__ float rs[kR];
    if (threadIdx.x == 0) {
        int cc[kR] = {0, 0, 0, 0, 0, 0, 0, 0};
        for (int e = e0; e < e1; ++e) cc[erec[e] & 7]++;
#pragma unroll
        for (int r = 0; r < kR; ++r) rs[r] = 1.0f / fmaxf((float)cc[r], 1.0f);
    }
    __syncthreads();

    ushort4 rv = *reinterpret_cast<const ushort4*>(y + (size_t)d * kKy + c);
    float4 bv = *reinterpret_cast<const float4*>(bias + c);
    float4 acc = make_float4(bf2f(rv.x) + bv.x, bf2f(rv.y) + bv.y,
                             bf2f(rv.z) + bv.z, bf2f(rv.w) + bv.w);

    for (int e = e0; e < e1; ++e) {
        int rec = erec[e];              // uniform across block
        int rel = rec & 7;
        int s = rec >> 3;
        float sc = rs[rel];             // LDS broadcast
        ushort4 v = *reinterpret_cast<const ushort4*>(
            y + (size_t)s * kKy + ((rel + 1) << 10) + c);
        acc.x += sc * bf2f(v.x); acc.y += sc * bf2f(v.y);
        acc.z += sc * bf2f(v.z); acc.w += sc * bf2f(v.w);
    }
    *reinterpret_cast<ushort4*>(ga + (size_t)d * kKz + c) = f2bf4(acc);
}

// C = A[M,K]bf16 @ Bt[Ncols,K]bf16^T (+bias). 128x128 tile, BK=32, 4 waves.
// OPERAND-SWAPPED MFMA: mfma(bfr, af, acc) yields the transposed C/D fragment:
//   lane holds C[row = i*16 + (lane&15)][col = j*16 + (lane>>4)*4 + reg]
// -> 4 acc regs = 4 consecutive columns -> 8B/16B vectorized epilogue stores.
// MODE 0: store f2bf(acc+bias) into Cbf (ld ldc)
// MODE 1: z=acc+bias; h=tanh(u)*z + x*(1-z) -> Cf
template <int MODE>
__global__ __launch_bounds__(256) void gemm_mfma(
    const u16* __restrict__ A, int lda,
    const u16* __restrict__ Bt, int ldb, int K,
    int M, int Ncols, const float* __restrict__ bias,
    u16* __restrict__ Cbf, int ldc,
    float* __restrict__ Cf, const u16* __restrict__ uga, const float* __restrict__ xo)
{
    __shared__ u16 sA[128 * 32];
    __shared__ u16 sB[128 * 32];

    const int tid = threadIdx.x;
    const int wave = tid >> 6;
    const int lane = tid & 63;

    const int row0 = blockIdx.y * 128;
    const int col0 = blockIdx.x * 128;

    const int srow = wave * 16 + (lane >> 2);
    const int scol = (lane & 3) * 8;

    const u16* gA0 = A + (size_t)(row0 + srow) * lda + scol;
    const u16* gA1 = A + (size_t)(row0 + 64 + srow) * lda + scol;
    const u16* gB0 = Bt + (size_t)(col0 + srow) * ldb + scol;
    const u16* gB1 = Bt + (size_t)(col0 + 64 + srow) * ldb + scol;

    u16* lA0 = sA + (wave * 16) * 32;
    u16* lA1 = sA + (64 + wave * 16) * 32;
    u16* lB0 = sB + (wave * 16) * 32;
    u16* lB1 = sB + (64 + wave * 16) * 32;

    const int mq = (wave >> 1) * 64;
    const int nq = (wave & 1) * 64;
    const int fm = lane & 15;
    const int fk = (lane >> 4) * 8;

    f32x4 zf = {0.0f, 0.0f, 0.0f, 0.0f};
    f32x4 acc[4][4];
#pragma unroll
    for (int i = 0; i < 4; ++i)
#pragma unroll
        for (int j = 0; j < 4; ++j) acc[i][j] = zf;

    for (int k0 = 0; k0 < K; k0 += 32) {
        __syncthreads();
        __builtin_amdgcn_global_load_lds(GLB(gA0), LDSP(lA0), 16, 0, 0);
        __builtin_amdgcn_global_load_lds(GLB(gA1), LDSP(lA1), 16, 0, 0);
        __builtin_amdgcn_global_load_lds(GLB(gB0), LDSP(lB0), 16, 0, 0);
        __builtin_amdgcn_global_load_lds(GLB(gB1), LDSP(lB1), 16, 0, 0);
        gA0 += 32; gA1 += 32; gB0 += 32; gB1 += 32;
        __syncthreads();

        bf16x8 af[4], bfr[4];
#pragma unroll
        for (int i = 0; i < 4; ++i)
            af[i] = *reinterpret_cast<const bf16x8*>(&sA[(mq + i * 16 + fm) * 32 + fk]);
#pragma unroll
        for (int j = 0; j < 4; ++j)
            bfr[j] = *reinterpret_cast<const bf16x8*>(&sB[(nq + j * 16 + fm) * 32 + fk]);
#pragma unroll
        for (int i = 0; i < 4; ++i)
#pragma unroll
            for (int j = 0; j < 4; ++j)
                acc[i][j] = __builtin_amdgcn_mfma_f32_16x16x32_bf16(bfr[j], af[i], acc[i][j], 0, 0, 0);
    }

    // Transposed C/D fragment: row = i*16 + fm, col = j*16 + (lane>>4)*4 + reg
    const int cq = (lane >> 4) * 4;
#pragma unroll
    for (int i = 0; i < 4; ++i) {
        int row = row0 + mq + i * 16 + fm;
        if (row >= M) continue;
#pragma unroll
        for (int j = 0; j < 4; ++j) {
            int col = col0 + nq + j * 16 + cq;
            f32x4 v = acc[i][j];
            if (bias != nullptr) {
                float4 bv = *reinterpret_cast<const float4*>(bias + col);
                v[0] += bv.x; v[1] += bv.y; v[2] += bv.z; v[3] += bv.w;
            }
            if (MODE == 0) {
                ushort4 o;
                o.x = f2bf(v[0]); o.y = f2bf(v[1]); o.z = f2bf(v[2]); o.w = f2bf(v[3]);
                *reinterpret_cast<ushort4*>(Cbf + (size_t)row * ldc + col) = o;
            } else {
                ushort4 ur = *reinterpret_cast<const ushort4*>(uga + (size_t)row * kKz + col);
                float4 xr = *reinterpret_cast<const float4*>(xo + (size_t)row * kD + col);
                float4 h;
                h.x = tanhf(bf2f(ur.x)) * v[0] + xr.x * (1.0f - v[0]);
                h.y = tanhf(bf2f(ur.y)) * v[1] + xr.y * (1.0f - v[1]);
                h.z = tanhf(bf2f(ur.z)) * v[2] + xr.z * (1.0f - v[2]);
                h.w = tanhf(bf2f(ur.w)) * v[3] + xr.w * (1.0f - v[3]);
                *reinterpret_cast<float4*>(Cf + (size_t)row * kD + col) = h;
            }
        }
    }
}

extern "C" void kernel_launch(void* const* d_in, const int* in_sizes, int n_in,
                              void* d_out, int out_size, void* d_ws, size_t ws_size,
                              hipStream_t stream) {
    (void)in_sizes; (void)n_in; (void)out_size; (void)ws_size;

    const float* x     = (const float*)d_in[0];
    const int* eidx    = (const int*)d_in[1];
    const int* etype   = (const int*)d_in[2];
    const float* weight= (const float*)d_in[3];
    const float* root  = (const float*)d_in[4];
    const float* bias  = (const float*)d_in[5];
    const float* wgate = (const float*)d_in[6];
    const float* bgate = (const float*)d_in[7];
    float* out = (float*)d_out;

    const int* src = eidx;
    const int* dst = eidx + kE;

    // ---- workspace ----
    char* ws = (char*)d_ws;
    size_t off = 0;
    u16* y    = (u16*)(ws + off);    off += (size_t)kNpad * kKy * 2;  // 186.4 MB
    u16* ga   = (u16*)(ws + off);    off += (size_t)kNpad * kKz * 2;  //  41.4 MB
    u16* Bt9  = (u16*)(ws + off);    off += (size_t)kKy * kD * 2;     //  18.9 MB
    u16* wg_t = (u16*)(ws + off);    off += (size_t)kD * kKz * 2;     //   4.2 MB
    int* cntd = (int*)(ws + off);    off += (size_t)kN * 4;
    int* rowp = (int*)(ws + off);    off += (size_t)(kN + 16) * 4;
    int* curs = (int*)(ws + off);    off += (size_t)kN * 4;
    int* erec = (int*)(ws + off);    off += (size_t)kE * 4;

    // CSR by dst
    zero16<<<16, 256, 0, stream>>>((uint4*)cntd, (long)kN * 4 / 16);
    hist_dst<<<(kE + 255) / 256, 256, 0, stream>>>(dst, cntd);
    scan_rowptr<<<1, 1024, 0, stream>>>(cntd, rowp, curs);
    fill_edges<<<(kE + 255) / 256, 256, 0, stream>>>(src, dst, etype, rowp, curs, erec);

    // zero padding rows [kN, kNpad) of ga (GEMMs read A rows unguarded)
    zero16<<<128, 256, 0, stream>>>((uint4*)(ga + (size_t)kN * kKz),
                                    (long)(kNpad - kN) * kKz * 2 / 16);

    // x -> bf16 into ga[:,1024:2048]
    cvt_x<<<kN, 256, 0, stream>>>(x, ga);

    // Bt9[n,k]: n in [0,1024) root^T; n in [1024(1+r), ...) W_r^T. wg_t[n,k]=wgate[k,n].
    {
        dim3 b(32, 8);
        transpose_to_bf16<<<dim3(kD / 32, kD / 32, 1), b, 0, stream>>>(root, Bt9, kD, kD, kD);
        transpose_to_bf16<<<dim3(kD / 32, kD / 32, kR), b, 0, stream>>>(
            weight, Bt9 + (size_t)kD * kD, kD, kD, kD);
        transpose_to_bf16<<<dim3(kD / 32, kKz / 32, 1), b, 0, stream>>>(wgate, wg_t, kKz, kD, kKz);
    }

    // GEMM1: y = [x] @ [root|W_0..W_7]  (A = x slice of ga, lda=2048)
    dim3 g1(kKy / 128, kNpad / 128);   // 72 x 79
    gemm_mfma<0><<<g1, 256, 0, stream>>>(ga + kD, kKz, Bt9, kD, kD, kN, kKy, nullptr,
                                         y, kKy, nullptr, nullptr, nullptr);

    // aggregate: u -> ga[:,0:1024] (bf16)
    aggregate<<<kN, 256, 0, stream>>>(y, bias, rowp, erec, ga);

    // GEMM2: z = ga @ wg_t + b_gate; h = tanh(u)*z + x*(1-z) -> out
    dim3 g2(kD / 128, kNpad / 128);    // 8 x 79
    gemm_mfma<1><<<g2, 256, 0, stream>>>(ga, kKz, wg_t, kKz, kKz, kN, kD, bgate,
                                         nullptr, 0, out, ga, x);
}

// Round 7
// 534.214 us; speedup vs baseline: 9.6415x; 1.0925x over previous
//
#include <hip/hip_runtime.h>
#include <math.h>

typedef unsigned short u16;
typedef __attribute__((ext_vector_type(8))) short bf16x8;   // 8 bf16 = 4 VGPRs
typedef __attribute__((ext_vector_type(4))) float f32x4;

static constexpr int kN = 10000;
static constexpr int kNpad = 10240;       // 40 * 256
static constexpr int kD = 1024;
static constexpr int kR = 8;
static constexpr int kE = 80000;
static constexpr int kKy = kD * (kR + 1); // 9216 : y = x @ [root | W_0..W_7]
static constexpr int kKz = 2 * kD;        // 2048 : [u | x]

#define GLB(p) ((const __attribute__((address_space(1))) unsigned int*)(const void*)(p))
#define LDSP(p) ((__attribute__((address_space(3))) unsigned int*)(p))

__device__ __forceinline__ u16 f2bf(float f) {
    union { float f; unsigned int i; } c; c.f = f;
    unsigned int u = c.i;
    return (u16)((u + 0x7FFFu + ((u >> 16) & 1u)) >> 16);   // RNE
}
__device__ __forceinline__ float bf2f(u16 u) {
    union { unsigned int i; float f; } c; c.i = ((unsigned int)u) << 16;
    return c.f;
}
__device__ __forceinline__ ushort4 f2bf4(float4 v) {
    ushort4 o; o.x = f2bf(v.x); o.y = f2bf(v.y); o.z = f2bf(v.z); o.w = f2bf(v.w);
    return o;
}

__global__ void zero16(uint4* __restrict__ p, long n16) {
    long i = (long)blockIdx.x * blockDim.x + threadIdx.x;
    long st = (long)gridDim.x * blockDim.x;
    uint4 z = make_uint4(0, 0, 0, 0);
    for (; i < n16; i += st) p[i] = z;
}

__global__ void hist_dst(const int* __restrict__ dst, int* __restrict__ cnt) {
    int e = blockIdx.x * blockDim.x + threadIdx.x;
    if (e < kE) atomicAdd(&cnt[dst[e]], 1);
}

// Single block, 1024 threads: exclusive scan of cnt[0..kN) -> rowptr[0..kN], zero cursor.
__global__ __launch_bounds__(1024) void scan_rowptr(const int* __restrict__ cnt,
                                                    int* __restrict__ rowptr,
                                                    int* __restrict__ cursor) {
    __shared__ int wsum[16];
    __shared__ int carry;
    const int tid = threadIdx.x;
    const int lane = tid & 63;
    const int w = tid >> 6;
    if (tid == 0) carry = 0;
    const int nchunk = (kN + 1024) / 1024;
    for (int ch = 0; ch < nchunk; ++ch) {
        int idx = ch * 1024 + tid;
        int v = (idx < kN) ? cnt[idx] : 0;
        int s = v;
#pragma unroll
        for (int off = 1; off < 64; off <<= 1) {
            int t = __shfl_up(s, off, 64);
            if (lane >= off) s += t;
        }
        if (lane == 63) wsum[w] = s;
        __syncthreads();
        if (w == 0 && lane < 16) {
            int t = wsum[lane];
#pragma unroll
            for (int off = 1; off < 16; off <<= 1) {
                int tt = __shfl_up(t, off, 64);
                if (lane >= off) t += tt;
            }
            wsum[lane] = t;
        }
        __syncthreads();
        int wpre = (w > 0) ? wsum[w - 1] : 0;
        int incl = s + wpre + carry;
        int excl = incl - v;
        if (idx <= kN) rowptr[idx] = excl;
        if (idx < kN) cursor[idx] = 0;
        __syncthreads();
        if (tid == 1023) carry = incl;
        __syncthreads();
    }
}

__global__ void fill_edges(const int* __restrict__ src, const int* __restrict__ dst,
                           const int* __restrict__ etype, const int* __restrict__ rowptr,
                           int* __restrict__ cursor, int* __restrict__ erec) {
    int e = blockIdx.x * blockDim.x + threadIdx.x;
    if (e < kE) {
        int d = dst[e];
        int pos = rowptr[d] + atomicAdd(&cursor[d], 1);
        erec[pos] = (src[e] << 3) | etype[e];
    }
}

// x fp32 -> bf16 into ga[:,1024:2048].
__global__ void cvt_x(const float* __restrict__ x, u16* __restrict__ ga) {
    int row = blockIdx.x;
    int c = threadIdx.x << 2;
    float4 v = *reinterpret_cast<const float4*>(x + (size_t)row * kD + c);
    *reinterpret_cast<ushort4*>(ga + (size_t)row * kKz + kD + c) = f2bf4(v);
}

// S [rows][cols] fp32 -> D[n*ldD + k] = S[k, n] bf16. Batched square blocks.
__global__ void transpose_to_bf16(const float* __restrict__ S, u16* __restrict__ D,
                                  int rows, int cols, int ldD) {
    S += (size_t)blockIdx.z * rows * cols;
    D += (size_t)blockIdx.z * rows * cols;
    __shared__ float t[32][33];
    int c0 = blockIdx.x * 32, r0 = blockIdx.y * 32;
    int x = threadIdx.x, y = threadIdx.y;   // block (32,8)
#pragma unroll
    for (int i = 0; i < 32; i += 8)
        t[y + i][x] = S[(size_t)(r0 + y + i) * cols + c0 + x];
    __syncthreads();
#pragma unroll
    for (int i = 0; i < 32; i += 8)
        D[(size_t)(c0 + y + i) * ldD + r0 + x] = f2bf(t[x][y + i]);
}

// One block (256 thr) per dst row: u[d] = y[d,root] + bias + sum_e rs[rel]*y[src,rel].
// Writes u bf16 into ga[:,0:1024].
__global__ __launch_bounds__(256) void aggregate(const u16* __restrict__ y,
                                                 const float* __restrict__ bias,
                                                 const int* __restrict__ rowptr,
                                                 const int* __restrict__ erec,
                                                 u16* __restrict__ ga) {
    const int d = blockIdx.x;
    const int c = threadIdx.x << 2;
    const int e0 = rowptr[d], e1 = rowptr[d + 1];

    __shared__ float rs[kR];
    if (threadIdx.x == 0) {
        int cc[kR] = {0, 0, 0, 0, 0, 0, 0, 0};
        for (int e = e0; e < e1; ++e) cc[erec[e] & 7]++;
#pragma unroll
        for (int r = 0; r < kR; ++r) rs[r] = 1.0f / fmaxf((float)cc[r], 1.0f);
    }
    __syncthreads();

    ushort4 rv = *reinterpret_cast<const ushort4*>(y + (size_t)d * kKy + c);
    float4 bv = *reinterpret_cast<const float4*>(bias + c);
    float4 acc = make_float4(bf2f(rv.x) + bv.x, bf2f(rv.y) + bv.y,
                             bf2f(rv.z) + bv.z, bf2f(rv.w) + bv.w);

    for (int e = e0; e < e1; ++e) {
        int rec = erec[e];              // uniform across block
        int rel = rec & 7;
        int s = rec >> 3;
        float sc = rs[rel];             // LDS broadcast
        ushort4 v = *reinterpret_cast<const ushort4*>(
            y + (size_t)s * kKy + ((rel + 1) << 10) + c);
        acc.x += sc * bf2f(v.x); acc.y += sc * bf2f(v.y);
        acc.z += sc * bf2f(v.z); acc.w += sc * bf2f(v.w);
    }
    *reinterpret_cast<ushort4*>(ga + (size_t)d * kKz + c) = f2bf4(acc);
}

// GEMM1 kernel: C = A[M,K]bf16 @ Bt[Ncols,K]^T, bf16 out. Block tile 256x128,
// BK=32, 4 waves, each wave 128x64 (8x4 MFMA 16x16x32, operand-swapped).
// LDS: sA 16KB + sB 8KB. 32 MFMA per 12 frag-loads (vs 16:8) -> LDS-issue bound
// relief. A rows must be padded to gridDim.y*256.
__global__ __launch_bounds__(256, 2) void gemm_mfma_256(
    const u16* __restrict__ A, int lda,
    const u16* __restrict__ Bt, int ldb, int K,
    int M, u16* __restrict__ Cbf, int ldc)
{
    __shared__ u16 sA[256 * 32];
    __shared__ u16 sB[128 * 32];

    const int tid = threadIdx.x;
    const int wave = tid >> 6;
    const int lane = tid & 63;

    const int row0 = blockIdx.y * 256;
    const int col0 = blockIdx.x * 128;

    const int srow4 = lane >> 2;       // 0..15
    const int scol = (lane & 3) * 8;   // 16B chunk

    // A staging: 16 DMA slots of 16 rows; wave w owns slots w*4..w*4+3.
    const u16* gA[4];
    u16* lA[4];
#pragma unroll
    for (int q = 0; q < 4; ++q) {
        int r = wave * 64 + q * 16;
        gA[q] = A + (size_t)(row0 + r + srow4) * lda + scol;
        lA[q] = sA + (r)*32;
    }
    // B staging: 8 slots; wave w owns rows wave*16 + p*64, p=0,1.
    const u16* gB[2];
    u16* lB[2];
#pragma unroll
    for (int p = 0; p < 2; ++p) {
        int r = p * 64 + wave * 16;
        gB[p] = Bt + (size_t)(col0 + r + srow4) * ldb + scol;
        lB[p] = sB + (r)*32;
    }

    const int mq = (wave >> 1) * 128;  // wave row-half (128 rows)
    const int nq = (wave & 1) * 64;    // wave col-half (64 cols)
    const int fm = lane & 15;
    const int fk = (lane >> 4) * 8;

    f32x4 zf = {0.0f, 0.0f, 0.0f, 0.0f};
    f32x4 acc[8][4];
#pragma unroll
    for (int i = 0; i < 8; ++i)
#pragma unroll
        for (int j = 0; j < 4; ++j) acc[i][j] = zf;

    for (int k0 = 0; k0 < K; k0 += 32) {
        __syncthreads();
#pragma unroll
        for (int q = 0; q < 4; ++q)
            __builtin_amdgcn_global_load_lds(GLB(gA[q]), LDSP(lA[q]), 16, 0, 0);
#pragma unroll
        for (int p = 0; p < 2; ++p)
            __builtin_amdgcn_global_load_lds(GLB(gB[p]), LDSP(lB[p]), 16, 0, 0);
#pragma unroll
        for (int q = 0; q < 4; ++q) gA[q] += 32;
#pragma unroll
        for (int p = 0; p < 2; ++p) gB[p] += 32;
        __syncthreads();

        bf16x8 af[8], bfr[4];
#pragma unroll
        for (int i = 0; i < 8; ++i)
            af[i] = *reinterpret_cast<const bf16x8*>(&sA[(mq + i * 16 + fm) * 32 + fk]);
#pragma unroll
        for (int j = 0; j < 4; ++j)
            bfr[j] = *reinterpret_cast<const bf16x8*>(&sB[(nq + j * 16 + fm) * 32 + fk]);
#pragma unroll
        for (int i = 0; i < 8; ++i)
#pragma unroll
            for (int j = 0; j < 4; ++j)
                acc[i][j] = __builtin_amdgcn_mfma_f32_16x16x32_bf16(bfr[j], af[i], acc[i][j], 0, 0, 0);
    }

    // Transposed C/D: row = mq + i*16 + fm, col = nq + j*16 + (lane>>4)*4 + reg
    const int cq = (lane >> 4) * 4;
#pragma unroll
    for (int i = 0; i < 8; ++i) {
        int row = row0 + mq + i * 16 + fm;
        if (row >= M) continue;
#pragma unroll
        for (int j = 0; j < 4; ++j) {
            int col = col0 + nq + j * 16 + cq;
            f32x4 v = acc[i][j];
            ushort4 o;
            o.x = f2bf(v[0]); o.y = f2bf(v[1]); o.z = f2bf(v[2]); o.w = f2bf(v[3]);
            *reinterpret_cast<ushort4*>(Cbf + (size_t)row * ldc + col) = o;
        }
    }
}

// GEMM2 kernel: 128x128 tile, BK=32, 4 waves, wave 64x64. Operand-swapped.
// z = A @ Bt^T + bias; h = tanh(u)*z + x*(1-z) -> Cf (fused combine epilogue).
__global__ __launch_bounds__(256) void gemm_mfma_gate(
    const u16* __restrict__ A, int lda,
    const u16* __restrict__ Bt, int ldb, int K,
    int M, const float* __restrict__ bias,
    float* __restrict__ Cf, const u16* __restrict__ uga, const float* __restrict__ xo)
{
    __shared__ u16 sA[128 * 32];
    __shared__ u16 sB[128 * 32];

    const int tid = threadIdx.x;
    const int wave = tid >> 6;
    const int lane = tid & 63;

    const int row0 = blockIdx.y * 128;
    const int col0 = blockIdx.x * 128;

    const int srow = wave * 16 + (lane >> 2);
    const int scol = (lane & 3) * 8;

    const u16* gA0 = A + (size_t)(row0 + srow) * lda + scol;
    const u16* gA1 = A + (size_t)(row0 + 64 + srow) * lda + scol;
    const u16* gB0 = Bt + (size_t)(col0 + srow) * ldb + scol;
    const u16* gB1 = Bt + (size_t)(col0 + 64 + srow) * ldb + scol;

    u16* lA0 = sA + (wave * 16) * 32;
    u16* lA1 = sA + (64 + wave * 16) * 32;
    u16* lB0 = sB + (wave * 16) * 32;
    u16* lB1 = sB + (64 + wave * 16) * 32;

    const int mq = (wave >> 1) * 64;
    const int nq = (wave & 1) * 64;
    const int fm = lane & 15;
    const int fk = (lane >> 4) * 8;

    f32x4 zf = {0.0f, 0.0f, 0.0f, 0.0f};
    f32x4 acc[4][4];
#pragma unroll
    for (int i = 0; i < 4; ++i)
#pragma unroll
        for (int j = 0; j < 4; ++j) acc[i][j] = zf;

    for (int k0 = 0; k0 < K; k0 += 32) {
        __syncthreads();
        __builtin_amdgcn_global_load_lds(GLB(gA0), LDSP(lA0), 16, 0, 0);
        __builtin_amdgcn_global_load_lds(GLB(gA1), LDSP(lA1), 16, 0, 0);
        __builtin_amdgcn_global_load_lds(GLB(gB0), LDSP(lB0), 16, 0, 0);
        __builtin_amdgcn_global_load_lds(GLB(gB1), LDSP(lB1), 16, 0, 0);
        gA0 += 32; gA1 += 32; gB0 += 32; gB1 += 32;
        __syncthreads();

        bf16x8 af[4], bfr[4];
#pragma unroll
        for (int i = 0; i < 4; ++i)
            af[i] = *reinterpret_cast<const bf16x8*>(&sA[(mq + i * 16 + fm) * 32 + fk]);
#pragma unroll
        for (int j = 0; j < 4; ++j)
            bfr[j] = *reinterpret_cast<const bf16x8*>(&sB[(nq + j * 16 + fm) * 32 + fk]);
#pragma unroll
        for (int i = 0; i < 4; ++i)
#pragma unroll
            for (int j = 0; j < 4; ++j)
                acc[i][j] = __builtin_amdgcn_mfma_f32_16x16x32_bf16(bfr[j], af[i], acc[i][j], 0, 0, 0);
    }

    const int cq = (lane >> 4) * 4;
#pragma unroll
    for (int i = 0; i < 4; ++i) {
        int row = row0 + mq + i * 16 + fm;
        if (row >= M) continue;
#pragma unroll
        for (int j = 0; j < 4; ++j) {
            int col = col0 + nq + j * 16 + cq;
            f32x4 v = acc[i][j];
            float4 bv = *reinterpret_cast<const float4*>(bias + col);
            v[0] += bv.x; v[1] += bv.y; v[2] += bv.z; v[3] += bv.w;
            ushort4 ur = *reinterpret_cast<const ushort4*>(uga + (size_t)row * kKz + col);
            float4 xr = *reinterpret_cast<const float4*>(xo + (size_t)row * kD + col);
            float4 h;
            h.x = tanhf(bf2f(ur.x)) * v[0] + xr.x * (1.0f - v[0]);
            h.y = tanhf(bf2f(ur.y)) * v[1] + xr.y * (1.0f - v[1]);
            h.z = tanhf(bf2f(ur.z)) * v[2] + xr.z * (1.0f - v[2]);
            h.w = tanhf(bf2f(ur.w)) * v[3] + xr.w * (1.0f - v[3]);
            *reinterpret_cast<float4*>(Cf + (size_t)row * kD + col) = h;
        }
    }
}

extern "C" void kernel_launch(void* const* d_in, const int* in_sizes, int n_in,
                              void* d_out, int out_size, void* d_ws, size_t ws_size,
                              hipStream_t stream) {
    (void)in_sizes; (void)n_in; (void)out_size; (void)ws_size;

    const float* x     = (const float*)d_in[0];
    const int* eidx    = (const int*)d_in[1];
    const int* etype   = (const int*)d_in[2];
    const float* weight= (const float*)d_in[3];
    const float* root  = (const float*)d_in[4];
    const float* bias  = (const float*)d_in[5];
    const float* wgate = (const float*)d_in[6];
    const float* bgate = (const float*)d_in[7];
    float* out = (float*)d_out;

    const int* src = eidx;
    const int* dst = eidx + kE;

    // ---- workspace ----
    char* ws = (char*)d_ws;
    size_t off = 0;
    u16* y    = (u16*)(ws + off);    off += (size_t)kNpad * kKy * 2;  // 188.7 MB
    u16* ga   = (u16*)(ws + off);    off += (size_t)kNpad * kKz * 2;  //  41.9 MB
    u16* Bt9  = (u16*)(ws + off);    off += (size_t)kKy * kD * 2;     //  18.9 MB
    u16* wg_t = (u16*)(ws + off);    off += (size_t)kD * kKz * 2;     //   4.2 MB
    int* cntd = (int*)(ws + off);    off += (size_t)kN * 4;
    int* rowp = (int*)(ws + off);    off += (size_t)(kN + 16) * 4;
    int* curs = (int*)(ws + off);    off += (size_t)kN * 4;
    int* erec = (int*)(ws + off);    off += (size_t)kE * 4;

    // CSR by dst
    zero16<<<16, 256, 0, stream>>>((uint4*)cntd, (long)kN * 4 / 16);
    hist_dst<<<(kE + 255) / 256, 256, 0, stream>>>(dst, cntd);
    scan_rowptr<<<1, 1024, 0, stream>>>(cntd, rowp, curs);
    fill_edges<<<(kE + 255) / 256, 256, 0, stream>>>(src, dst, etype, rowp, curs, erec);

    // zero padding rows [kN, kNpad) of ga (GEMMs read A rows unguarded)
    zero16<<<256, 256, 0, stream>>>((uint4*)(ga + (size_t)kN * kKz),
                                    (long)(kNpad - kN) * kKz * 2 / 16);

    // x -> bf16 into ga[:,1024:2048]
    cvt_x<<<kN, 256, 0, stream>>>(x, ga);

    // Bt9[n,k]: n in [0,1024) root^T; n in [1024(1+r), ...) W_r^T. wg_t[n,k]=wgate[k,n].
    {
        dim3 b(32, 8);
        transpose_to_bf16<<<dim3(kD / 32, kD / 32, 1), b, 0, stream>>>(root, Bt9, kD, kD, kD);
        transpose_to_bf16<<<dim3(kD / 32, kD / 32, kR), b, 0, stream>>>(
            weight, Bt9 + (size_t)kD * kD, kD, kD, kD);
        transpose_to_bf16<<<dim3(kD / 32, kKz / 32, 1), b, 0, stream>>>(wgate, wg_t, kKz, kD, kKz);
    }

    // GEMM1: y = [x] @ [root|W_0..W_7]  (A = x slice of ga, lda=2048)
    dim3 g1(kKy / 128, kNpad / 256);   // 72 x 40
    gemm_mfma_256<<<g1, 256, 0, stream>>>(ga + kD, kKz, Bt9, kD, kD, kN, y, kKy);

    // aggregate: u -> ga[:,0:1024] (bf16)
    aggregate<<<kN, 256, 0, stream>>>(y, bias, rowp, erec, ga);

    // GEMM2: z = ga @ wg_t + b_gate; h = tanh(u)*z + x*(1-z) -> out
    dim3 g2(kD / 128, kNpad / 128);    // 8 x 80
    gemm_mfma_gate<<<g2, 256, 0, stream>>>(ga, kKz, wg_t, kKz, kKz, kN, bgate, out, ga, x);
}

// Round 8
// 496.597 us; speedup vs baseline: 10.3718x; 1.0757x over previous
//
#include <hip/hip_runtime.h>
#include <math.h>

typedef unsigned short u16;
typedef __attribute__((ext_vector_type(8))) short bf16x8;   // 8 bf16 = 4 VGPRs
typedef __attribute__((ext_vector_type(4))) float f32x4;

static constexpr int kN = 10000;
static constexpr int kNpad = 10240;       // 40 * 256 rows per relation range
static constexpr int kD = 1024;
static constexpr int kR = 8;
static constexpr int kE = 80000;
static constexpr int kKz = 2 * kD;        // 2048 : [u | x]
static constexpr int kCrows = kNpad * (kR + 1);  // 92160 compact y_c rows (worst case)
static constexpr int kTilesY = kCrows / 256;     // 360

#define GLB(p) ((const __attribute__((address_space(1))) unsigned int*)(const void*)(p))
#define LDSP(p) ((__attribute__((address_space(3))) unsigned int*)(p))

__device__ __forceinline__ u16 f2bf(float f) {
    union { float f; unsigned int i; } c; c.f = f;
    unsigned int u = c.i;
    return (u16)((u + 0x7FFFu + ((u >> 16) & 1u)) >> 16);   // RNE
}
__device__ __forceinline__ float bf2f(u16 u) {
    union { unsigned int i; float f; } c; c.i = ((unsigned int)u) << 16;
    return c.f;
}
__device__ __forceinline__ ushort4 f2bf4(float4 v) {
    ushort4 o; o.x = f2bf(v.x); o.y = f2bf(v.y); o.z = f2bf(v.z); o.w = f2bf(v.w);
    return o;
}

__global__ void zero16(uint4* __restrict__ p, long n16) {
    long i = (long)blockIdx.x * blockDim.x + threadIdx.x;
    long st = (long)gridDim.x * blockDim.x;
    uint4 z = make_uint4(0, 0, 0, 0);
    for (; i < n16; i += st) p[i] = z;
}

// Per edge: histogram dst (for CSR) and flag (rel, src) presence.
__global__ void mark_edges(const int* __restrict__ src, const int* __restrict__ dst,
                           const int* __restrict__ etype,
                           int* __restrict__ cntd, int* __restrict__ flag) {
    int e = blockIdx.x * blockDim.x + threadIdx.x;
    if (e < kE) {
        atomicAdd(&cntd[dst[e]], 1);
        flag[etype[e] * kN + src[e]] = 1;   // idempotent plain store
    }
}

// Single block, 1024 threads: exclusive scan of cnt[0..kN) -> rowptr[0..kN], zero cursor.
__global__ __launch_bounds__(1024) void scan_rowptr(const int* __restrict__ cnt,
                                                    int* __restrict__ rowptr,
                                                    int* __restrict__ cursor) {
    __shared__ int wsum[16];
    __shared__ int carry;
    const int tid = threadIdx.x;
    const int lane = tid & 63;
    const int w = tid >> 6;
    if (tid == 0) carry = 0;
    const int nchunk = (kN + 1024) / 1024;
    for (int ch = 0; ch < nchunk; ++ch) {
        int idx = ch * 1024 + tid;
        int v = (idx < kN) ? cnt[idx] : 0;
        int s = v;
#pragma unroll
        for (int off = 1; off < 64; off <<= 1) {
            int t = __shfl_up(s, off, 64);
            if (lane >= off) s += t;
        }
        if (lane == 63) wsum[w] = s;
        __syncthreads();
        if (w == 0 && lane < 16) {
            int t = wsum[lane];
#pragma unroll
            for (int off = 1; off < 16; off <<= 1) {
                int tt = __shfl_up(t, off, 64);
                if (lane >= off) t += tt;
            }
            wsum[lane] = t;
        }
        __syncthreads();
        int wpre = (w > 0) ? wsum[w - 1] : 0;
        int incl = s + wpre + carry;
        int excl = incl - v;
        if (idx <= kN) rowptr[idx] = excl;
        if (idx < kN) cursor[idx] = 0;
        __syncthreads();
        if (tid == 1023) carry = incl;
        __syncthreads();
    }
}

// 9 blocks x 1024 thr. Blocks 0..7: per-relation exclusive scan of flags ->
// sorted compact row list + pos table + count. Block 8: identity map for root.
__global__ __launch_bounds__(1024) void compact_scan(const int* __restrict__ flag,
                                                     int* __restrict__ row_src,
                                                     int* __restrict__ pos_tab,
                                                     int* __restrict__ relcnt9) {
    const int tid = threadIdx.x;
    if (blockIdx.x == kR) {   // root range: identity
        for (int i = tid; i < kNpad; i += 1024) row_src[i] = i;
        if (tid == 0) relcnt9[0] = kN;
        return;
    }
    const int r = blockIdx.x;
    const int base = kNpad * (r + 1);
    __shared__ int wsum[16];
    __shared__ int carry;
    const int lane = tid & 63;
    const int w = tid >> 6;
    if (tid == 0) carry = 0;
    const int nchunk = (kN + 1023) / 1024;
    for (int ch = 0; ch < nchunk; ++ch) {
        int idx = ch * 1024 + tid;
        int v = (idx < kN) ? flag[r * kN + idx] : 0;
        int s = v;
#pragma unroll
        for (int off = 1; off < 64; off <<= 1) {
            int t = __shfl_up(s, off, 64);
            if (lane >= off) s += t;
        }
        if (lane == 63) wsum[w] = s;
        __syncthreads();
        if (w == 0 && lane < 16) {
            int t = wsum[lane];
#pragma unroll
            for (int off = 1; off < 16; off <<= 1) {
                int tt = __shfl_up(t, off, 64);
                if (lane >= off) t += tt;
            }
            wsum[lane] = t;
        }
        __syncthreads();
        int wpre = (w > 0) ? wsum[w - 1] : 0;
        int incl = s + wpre + carry;
        int excl = incl - v;
        if (idx < kN && v) {
            row_src[base + excl] = idx;
            pos_tab[r * kN + idx] = base + excl;
        }
        __syncthreads();
        if (tid == 1023) carry = incl;
        __syncthreads();
    }
    if (tid == 0) relcnt9[r + 1] = carry;
}

// erec = (y_c row << 3) | rel, CSR-grouped by dst.
__global__ void fill_edges(const int* __restrict__ src, const int* __restrict__ dst,
                           const int* __restrict__ etype, const int* __restrict__ rowptr,
                           int* __restrict__ cursor, const int* __restrict__ pos_tab,
                           int* __restrict__ erec) {
    int e = blockIdx.x * blockDim.x + threadIdx.x;
    if (e < kE) {
        int d = dst[e], r = etype[e], s = src[e];
        int pos = rowptr[d] + atomicAdd(&cursor[d], 1);
        erec[pos] = (pos_tab[r * kN + s] << 3) | r;
    }
}

// x fp32 -> bf16 into ga[:,1024:2048].
__global__ void cvt_x(const float* __restrict__ x, u16* __restrict__ ga) {
    int row = blockIdx.x;
    int c = threadIdx.x << 2;
    float4 v = *reinterpret_cast<const float4*>(x + (size_t)row * kD + c);
    *reinterpret_cast<ushort4*>(ga + (size_t)row * kKz + kD + c) = f2bf4(v);
}

// S [rows][cols] fp32 -> D[n*ldD + k] = S[k, n] bf16. Batched square blocks.
__global__ void transpose_to_bf16(const float* __restrict__ S, u16* __restrict__ D,
                                  int rows, int cols, int ldD) {
    S += (size_t)blockIdx.z * rows * cols;
    D += (size_t)blockIdx.z * rows * cols;
    __shared__ float t[32][33];
    int c0 = blockIdx.x * 32, r0 = blockIdx.y * 32;
    int x = threadIdx.x, y = threadIdx.y;   // block (32,8)
#pragma unroll
    for (int i = 0; i < 32; i += 8)
        t[y + i][x] = S[(size_t)(r0 + y + i) * cols + c0 + x];
    __syncthreads();
#pragma unroll
    for (int i = 0; i < 32; i += 8)
        D[(size_t)(c0 + y + i) * ldD + r0 + x] = f2bf(t[x][y + i]);
}

// One block (256 thr) per dst row: u[d] = y_c[d] + bias + sum_e rs[rel]*y_c[pos].
// Writes u bf16 into ga[:,0:1024].
__global__ __launch_bounds__(256) void aggregate(const u16* __restrict__ yc,
                                                 const float* __restrict__ bias,
                                                 const int* __restrict__ rowptr,
                                                 const int* __restrict__ erec,
                                                 u16* __restrict__ ga) {
    const int d = blockIdx.x;
    const int c = threadIdx.x << 2;
    const int e0 = rowptr[d], e1 = rowptr[d + 1];

    __shared__ float rs[kR];
    if (threadIdx.x == 0) {
        int cc[kR] = {0, 0, 0, 0, 0, 0, 0, 0};
        for (int e = e0; e < e1; ++e) cc[erec[e] & 7]++;
#pragma unroll
        for (int r = 0; r < kR; ++r) rs[r] = 1.0f / fmaxf((float)cc[r], 1.0f);
    }
    __syncthreads();

    ushort4 rv = *reinterpret_cast<const ushort4*>(yc + (size_t)d * kD + c);
    float4 bv = *reinterpret_cast<const float4*>(bias + c);
    float4 acc = make_float4(bf2f(rv.x) + bv.x, bf2f(rv.y) + bv.y,
                             bf2f(rv.z) + bv.z, bf2f(rv.w) + bv.w);

    for (int e = e0; e < e1; ++e) {
        int rec = erec[e];              // uniform across block
        int rel = rec & 7;
        int pos = rec >> 3;
        float sc = rs[rel];             // LDS broadcast
        ushort4 v = *reinterpret_cast<const ushort4*>(yc + (size_t)pos * kD + c);
        acc.x += sc * bf2f(v.x); acc.y += sc * bf2f(v.y);
        acc.z += sc * bf2f(v.z); acc.w += sc * bf2f(v.w);
    }
    *reinterpret_cast<ushort4*>(ga + (size_t)d * kKz + c) = f2bf4(acc);
}

// GEMM1 (compacted): y_c[grow] = x_bf[row_src[grow]] @ W_{rel(grow)}^T.
// Block tile 256x128, BK=32, 4 waves (each 128x64, operand-swapped MFMA).
// blockIdx.y = global row tile t; relidx = t/40 picks B = Bt9 + relidx*1024 rows.
// Tiles past the relation's compacted count exit early (device-side count).
__global__ __launch_bounds__(256, 2) void gemm_compact(
    const u16* __restrict__ xb, int ldx,
    const u16* __restrict__ Bt9,
    const int* __restrict__ row_src, const int* __restrict__ relcnt9,
    u16* __restrict__ yc)
{
    const int t = blockIdx.y;
    const int relidx = t / 40;
    const int lt = t - relidx * 40;
    if (lt * 256 >= relcnt9[relidx]) return;   // uniform early-exit (before barriers)

    __shared__ u16 sA[256 * 32];
    __shared__ u16 sB[128 * 32];

    const int tid = threadIdx.x;
    const int wave = tid >> 6;
    const int lane = tid & 63;

    const int row0 = t * 256;
    const int col0 = blockIdx.x * 128;

    const int srow4 = lane >> 2;       // 0..15
    const int scol = (lane & 3) * 8;   // 16B chunk

    // A staging: gather rows via row_src (per-lane global addr; LDS dest lane-ordered)
    const u16* gA[4];
    u16* lA[4];
#pragma unroll
    for (int q = 0; q < 4; ++q) {
        int r = wave * 64 + q * 16;
        int srcrow = row_src[row0 + r + srow4];
        gA[q] = xb + (size_t)srcrow * ldx + scol;
        lA[q] = sA + r * 32;
    }
    const u16* gB[2];
    u16* lB[2];
#pragma unroll
    for (int p = 0; p < 2; ++p) {
        int r = p * 64 + wave * 16;
        gB[p] = Bt9 + (size_t)(relidx * kD + col0 + r + srow4) * kD + scol;
        lB[p] = sB + r * 32;
    }

    const int mq = (wave >> 1) * 128;
    const int nq = (wave & 1) * 64;
    const int fm = lane & 15;
    const int fk = (lane >> 4) * 8;

    f32x4 zf = {0.0f, 0.0f, 0.0f, 0.0f};
    f32x4 acc[8][4];
#pragma unroll
    for (int i = 0; i < 8; ++i)
#pragma unroll
        for (int j = 0; j < 4; ++j) acc[i][j] = zf;

    for (int k0 = 0; k0 < kD; k0 += 32) {
        __syncthreads();
#pragma unroll
        for (int q = 0; q < 4; ++q)
            __builtin_amdgcn_global_load_lds(GLB(gA[q]), LDSP(lA[q]), 16, 0, 0);
#pragma unroll
        for (int p = 0; p < 2; ++p)
            __builtin_amdgcn_global_load_lds(GLB(gB[p]), LDSP(lB[p]), 16, 0, 0);
#pragma unroll
        for (int q = 0; q < 4; ++q) gA[q] += 32;
#pragma unroll
        for (int p = 0; p < 2; ++p) gB[p] += 32;
        __syncthreads();

        bf16x8 af[8], bfr[4];
#pragma unroll
        for (int i = 0; i < 8; ++i)
            af[i] = *reinterpret_cast<const bf16x8*>(&sA[(mq + i * 16 + fm) * 32 + fk]);
#pragma unroll
        for (int j = 0; j < 4; ++j)
            bfr[j] = *reinterpret_cast<const bf16x8*>(&sB[(nq + j * 16 + fm) * 32 + fk]);
#pragma unroll
        for (int i = 0; i < 8; ++i)
#pragma unroll
            for (int j = 0; j < 4; ++j)
                acc[i][j] = __builtin_amdgcn_mfma_f32_16x16x32_bf16(bfr[j], af[i], acc[i][j], 0, 0, 0);
    }

    // Transposed C/D: row = mq + i*16 + fm, col = nq + j*16 + (lane>>4)*4 + reg
    const int cq = (lane >> 4) * 4;
#pragma unroll
    for (int i = 0; i < 8; ++i) {
        int row = row0 + mq + i * 16 + fm;   // y_c fully padded: no guard
#pragma unroll
        for (int j = 0; j < 4; ++j) {
            int col = col0 + nq + j * 16 + cq;
            f32x4 v = acc[i][j];
            ushort4 o;
            o.x = f2bf(v[0]); o.y = f2bf(v[1]); o.z = f2bf(v[2]); o.w = f2bf(v[3]);
            *reinterpret_cast<ushort4*>(yc + (size_t)row * kD + col) = o;
        }
    }
}

// GEMM2: 128x128 tile, BK=32, 4 waves, wave 64x64. Operand-swapped.
// z = A @ Bt^T + bias; h = tanh(u)*z + x*(1-z) -> Cf (fused combine).
__global__ __launch_bounds__(256) void gemm_mfma_gate(
    const u16* __restrict__ A, int lda,
    const u16* __restrict__ Bt, int ldb, int K,
    int M, const float* __restrict__ bias,
    float* __restrict__ Cf, const u16* __restrict__ uga, const float* __restrict__ xo)
{
    __shared__ u16 sA[128 * 32];
    __shared__ u16 sB[128 * 32];

    const int tid = threadIdx.x;
    const int wave = tid >> 6;
    const int lane = tid & 63;

    const int row0 = blockIdx.y * 128;
    const int col0 = blockIdx.x * 128;

    const int srow = wave * 16 + (lane >> 2);
    const int scol = (lane & 3) * 8;

    const u16* gA0 = A + (size_t)(row0 + srow) * lda + scol;
    const u16* gA1 = A + (size_t)(row0 + 64 + srow) * lda + scol;
    const u16* gB0 = Bt + (size_t)(col0 + srow) * ldb + scol;
    const u16* gB1 = Bt + (size_t)(col0 + 64 + srow) * ldb + scol;

    u16* lA0 = sA + (wave * 16) * 32;
    u16* lA1 = sA + (64 + wave * 16) * 32;
    u16* lB0 = sB + (wave * 16) * 32;
    u16* lB1 = sB + (64 + wave * 16) * 32;

    const int mq = (wave >> 1) * 64;
    const int nq = (wave & 1) * 64;
    const int fm = lane & 15;
    const int fk = (lane >> 4) * 8;

    f32x4 zf = {0.0f, 0.0f, 0.0f, 0.0f};
    f32x4 acc[4][4];
#pragma unroll
    for (int i = 0; i < 4; ++i)
#pragma unroll
        for (int j = 0; j < 4; ++j) acc[i][j] = zf;

    for (int k0 = 0; k0 < K; k0 += 32) {
        __syncthreads();
        __builtin_amdgcn_global_load_lds(GLB(gA0), LDSP(lA0), 16, 0, 0);
        __builtin_amdgcn_global_load_lds(GLB(gA1), LDSP(lA1), 16, 0, 0);
        __builtin_amdgcn_global_load_lds(GLB(gB0), LDSP(lB0), 16, 0, 0);
        __builtin_amdgcn_global_load_lds(GLB(gB1), LDSP(lB1), 16, 0, 0);
        gA0 += 32; gA1 += 32; gB0 += 32; gB1 += 32;
        __syncthreads();

        bf16x8 af[4], bfr[4];
#pragma unroll
        for (int i = 0; i < 4; ++i)
            af[i] = *reinterpret_cast<const bf16x8*>(&sA[(mq + i * 16 + fm) * 32 + fk]);
#pragma unroll
        for (int j = 0; j < 4; ++j)
            bfr[j] = *reinterpret_cast<const bf16x8*>(&sB[(nq + j * 16 + fm) * 32 + fk]);
#pragma unroll
        for (int i = 0; i < 4; ++i)
#pragma unroll
            for (int j = 0; j < 4; ++j)
                acc[i][j] = __builtin_amdgcn_mfma_f32_16x16x32_bf16(bfr[j], af[i], acc[i][j], 0, 0, 0);
    }

    const int cq = (lane >> 4) * 4;
#pragma unroll
    for (int i = 0; i < 4; ++i) {
        int row = row0 + mq + i * 16 + fm;
        if (row >= M) continue;
#pragma unroll
        for (int j = 0; j < 4; ++j) {
            int col = col0 + nq + j * 16 + cq;
            f32x4 v = acc[i][j];
            float4 bv = *reinterpret_cast<const float4*>(bias + col);
            v[0] += bv.x; v[1] += bv.y; v[2] += bv.z; v[3] += bv.w;
            ushort4 ur = *reinterpret_cast<const ushort4*>(uga + (size_t)row * kKz + col);
            float4 xr = *reinterpret_cast<const float4*>(xo + (size_t)row * kD + col);
            float4 h;
            h.x = tanhf(bf2f(ur.x)) * v[0] + xr.x * (1.0f - v[0]);
            h.y = tanhf(bf2f(ur.y)) * v[1] + xr.y * (1.0f - v[1]);
            h.z = tanhf(bf2f(ur.z)) * v[2] + xr.z * (1.0f - v[2]);
            h.w = tanhf(bf2f(ur.w)) * v[3] + xr.w * (1.0f - v[3]);
            *reinterpret_cast<float4*>(Cf + (size_t)row * kD + col) = h;
        }
    }
}

extern "C" void kernel_launch(void* const* d_in, const int* in_sizes, int n_in,
                              void* d_out, int out_size, void* d_ws, size_t ws_size,
                              hipStream_t stream) {
    (void)in_sizes; (void)n_in; (void)out_size; (void)ws_size;

    const float* x     = (const float*)d_in[0];
    const int* eidx    = (const int*)d_in[1];
    const int* etype   = (const int*)d_in[2];
    const float* weight= (const float*)d_in[3];
    const float* root  = (const float*)d_in[4];
    const float* bias  = (const float*)d_in[5];
    const float* wgate = (const float*)d_in[6];
    const float* bgate = (const float*)d_in[7];
    float* out = (float*)d_out;

    const int* src = eidx;
    const int* dst = eidx + kE;

    // ---- workspace ----
    char* ws = (char*)d_ws;
    size_t off = 0;
    u16* yc   = (u16*)(ws + off);    off += (size_t)kCrows * kD * 2;   // 188.7 MB
    u16* ga   = (u16*)(ws + off);    off += (size_t)kNpad * kKz * 2;   //  41.9 MB
    u16* Bt9  = (u16*)(ws + off);    off += (size_t)(kR + 1) * kD * kD * 2; // 18.9 MB
    u16* wg_t = (u16*)(ws + off);    off += (size_t)kD * kKz * 2;      //   4.2 MB
    // int metadata (cntd|flag|row_src zeroed in one pass; all counts %4==0)
    int* cntd    = (int*)(ws + off); off += (size_t)kN * 4;            // 10000
    int* flag    = (int*)(ws + off); off += (size_t)kR * kN * 4;       // 80000
    int* row_src = (int*)(ws + off); off += (size_t)kCrows * 4;        // 92160
    int* pos_tab = (int*)(ws + off); off += (size_t)kR * kN * 4;
    int* rowp    = (int*)(ws + off); off += (size_t)(kN + 16) * 4;
    int* curs    = (int*)(ws + off); off += (size_t)kN * 4;
    int* erec    = (int*)(ws + off); off += (size_t)kE * 4;
    int* relcnt9 = (int*)(ws + off); off += 16 * 4;

    // zero cntd+flag+row_src in one pass (contiguous, 182160 ints)
    zero16<<<180, 256, 0, stream>>>((uint4*)cntd, (long)(kN + kR * kN + kCrows) / 4);

    mark_edges<<<(kE + 255) / 256, 256, 0, stream>>>(src, dst, etype, cntd, flag);
    scan_rowptr<<<1, 1024, 0, stream>>>(cntd, rowp, curs);
    compact_scan<<<kR + 1, 1024, 0, stream>>>(flag, row_src, pos_tab, relcnt9);
    fill_edges<<<(kE + 255) / 256, 256, 0, stream>>>(src, dst, etype, rowp, curs,
                                                     pos_tab, erec);

    // zero padding rows [kN, kNpad) of ga (GEMM2 + gathers read them unguarded)
    zero16<<<256, 256, 0, stream>>>((uint4*)(ga + (size_t)kN * kKz),
                                    (long)(kNpad - kN) * kKz * 2 / 16);

    // x -> bf16 into ga[:,1024:2048]
    cvt_x<<<kN, 256, 0, stream>>>(x, ga);

    // Bt9[n,k]: rows [0,1024) root^T; rows [1024(1+r),..) W_r^T. wg_t[n,k]=wgate[k,n].
    {
        dim3 b(32, 8);
        transpose_to_bf16<<<dim3(kD / 32, kD / 32, 1), b, 0, stream>>>(root, Bt9, kD, kD, kD);
        transpose_to_bf16<<<dim3(kD / 32, kD / 32, kR), b, 0, stream>>>(
            weight, Bt9 + (size_t)kD * kD, kD, kD, kD);
        transpose_to_bf16<<<dim3(kD / 32, kKz / 32, 1), b, 0, stream>>>(wgate, wg_t, kKz, kD, kKz);
    }

    // GEMM1 (compacted): y_c = gathered x rows @ per-relation W
    dim3 g1(kD / 128, kTilesY);   // 8 x 360, ~2/3 exit early
    gemm_compact<<<g1, 256, 0, stream>>>(ga + kD, kKz, Bt9, row_src, relcnt9, yc);

    // aggregate: u -> ga[:,0:1024] (bf16)
    aggregate<<<kN, 256, 0, stream>>>(yc, bias, rowp, erec, ga);

    // GEMM2: z = ga @ wg_t + b_gate; h = tanh(u)*z + x*(1-z) -> out
    dim3 g2(kD / 128, kNpad / 128);    // 8 x 80
    gemm_mfma_gate<<<g2, 256, 0, stream>>>(ga, kKz, wg_t, kKz, kKz, kN, bgate, out, ga, x);
}